// Round 2
// baseline (1044.863 us; speedup 1.0000x reference)
//
#include <hip/hip_runtime.h>
#include <hip/hip_bf16.h>
#include <hip/hip_cooperative_groups.h>

namespace cg = cooperative_groups;

#define N_NODES 20000
#define NEDGE   320000
#define DIM     128
#define NH      4
#define HD      512   // NH*DIM
#define LAYERS  3
#define EPS_RMS 1.1920929e-07f
#define SLOPE   0.2f
#define NTILES  (N_NODES >> 4)   // 1250

#define NWGC  (LAYERS * DIM * HD)    // 196608
#define NW1C  (LAYERS * DIM * DIM)   // 49152
#define NVC   (LAYERS * DIM)         // 384
#define NPACK (NWGC + 2 * NW1C + 5 * NVC)   // 296832

#define SMEM_BYTES 23552

typedef __bf16 bf16_t;
typedef __bf16 bf16v2 __attribute__((ext_vector_type(2)));
typedef __bf16 bf16v8 __attribute__((ext_vector_type(8)));
typedef float  f32v4  __attribute__((ext_vector_type(4)));
typedef float  f32v2  __attribute__((ext_vector_type(2)));

__device__ __forceinline__ int clamp_node(int s) {
    return ((unsigned)s >= (unsigned)N_NODES) ? 0 : s;
}
__device__ __forceinline__ float leaky(float e) { return e > 0.f ? e : SLOPE * e; }
__device__ __forceinline__ unsigned char enc_fp8(float v) {
    int p = __builtin_amdgcn_cvt_pk_fp8_f32(v, v, 0, false);
    return (unsigned char)(p & 0xff);
}
__device__ __forceinline__ unsigned short enc_fp8_pair(float a, float b) {
    int p = __builtin_amdgcn_cvt_pk_fp8_f32(a, b, 0, false);
    return (unsigned short)(p & 0xffff);
}

// ---- per-wave dtype detection ----
__device__ __forceinline__ bool wave_detect_bf16(const unsigned short* xh) {
    int lane = threadIdx.x & 63;
    unsigned short hw = xh[2 * lane];
    int e = (hw >> 7) & 0xff;
    unsigned long long b = __ballot(e >= 96 && e <= 140);
    return __popcll(b) >= 48;
}
__device__ __forceinline__ bool wave_detect_i64(const int* ei) {
    int lane = threadIdx.x & 63;
    unsigned long long b = __ballot(ei[2 * lane + 1] != 0);
    return b == 0ULL;
}
__device__ __forceinline__ float raw_elem(const void* in, size_t j, bool isbf) {
    return isbf ? (float)((const bf16_t*)in)[j] : ((const float*)in)[j];
}
__device__ __forceinline__ bf16_t cvt_elem(const void* in, size_t j, bool isbf) {
    return isbf ? ((const bf16_t*)in)[j] : (bf16_t)((const float*)in)[j];
}
__device__ __forceinline__ int edge_src(const int* ei, int e, bool is64) {
    return clamp_node(is64 ? ei[2 * e] : ei[e]);
}
__device__ __forceinline__ int edge_dst(const int* ei, int e, bool is64) {
    return clamp_node(is64 ? ei[2 * NEDGE + 2 * e] : ei[NEDGE + e]);
}

// ================= shared work bodies =================

// weight fragment-pack + small-vector convert; item space [0, NPACK)
__device__ __forceinline__ void pack_item(int i, bool isbf,
        const void* Wg, const void* W1, const void* W2,
        const void* bg, const void* b1, const void* b2,
        const void* n1, const void* n2,
        bf16_t* WmixP, bf16_t* W1P, bf16_t* W2P,
        bf16_t* bgc, bf16_t* b1c, bf16_t* b2c, bf16_t* n1c, bf16_t* n2c) {
    if (i < NWGC) {   // Wmix fragment-packed
        int l = i >> 16;
        int r = i & 65535;
        int j = r & 7;
        int lane2 = (r >> 3) & 63;
        int mm = lane2 & 15, kqq = lane2 >> 4;
        int tt = (r >> 9) & 1;
        int kk = (r >> 10) & 15;
        int wvv = r >> 14;
        int kidx = kk * 32 + kqq * 8 + j;
        int h = kidx >> 7, kp = kidx & 127;
        int c = 32 * wvv + tt * 16 + mm;
        WmixP[i] = cvt_elem(Wg, (size_t)l * DIM * HD + (size_t)kp * HD + h * DIM + c, isbf);
        return;
    }
    i -= NWGC;
    if (i < NW1C) {
        int l = i / 16384;
        int r = i & 16383;
        int j = r & 7;
        int lane2 = (r >> 3) & 63;
        int mm = lane2 & 15, kqq = lane2 >> 4;
        int tt = (r >> 9) & 1;
        int ks = (r >> 10) & 3;
        int wvv = r >> 12;
        int k = ks * 32 + kqq * 8 + j;
        int c = 32 * wvv + tt * 16 + mm;
        W1P[i] = cvt_elem(W1, (size_t)l * DIM * DIM + (size_t)k * DIM + c, isbf);
        return;
    }
    i -= NW1C;
    if (i < NW1C) {
        int l = i / 16384;
        int r = i & 16383;
        int j = r & 7;
        int lane2 = (r >> 3) & 63;
        int mm = lane2 & 15, kqq = lane2 >> 4;
        int tt = (r >> 9) & 1;
        int ks = (r >> 10) & 3;
        int wvv = r >> 12;
        int k = ks * 32 + kqq * 8 + j;
        int c = 32 * wvv + tt * 16 + mm;
        W2P[i] = cvt_elem(W2, (size_t)l * DIM * DIM + (size_t)k * DIM + c, isbf);
        return;
    }
    i -= NW1C;
    if (i >= 5 * NVC) return;
    int seg = i / NVC, k = i - seg * NVC;
    if (seg == 0) bgc[k] = cvt_elem(bg, k, isbf);
    else if (seg == 1) b1c[k] = cvt_elem(b1, k, isbf);
    else if (seg == 2) b2c[k] = cvt_elem(b2, k, isbf);
    else if (seg == 3) n1c[k] = cvt_elem(n1, k, isbf);
    else n2c[k] = cvt_elem(n2, k, isbf);
}

// per-node a_s/a_d + fp8 pack (layer 0), one wave per node
__device__ __forceinline__ void asd_node(int n, int lane, bool isbf, const void* x,
        const float* __restrict__ vS, const float* __restrict__ vD,
        float* __restrict__ a_s, float* __restrict__ a_d,
        unsigned short* __restrict__ x8) {
    int c = 2 * lane;
    float f0 = raw_elem(x, (size_t)n * DIM + c, isbf);
    float f1 = raw_elem(x, (size_t)n * DIM + c + 1, isbf);
    x8[n * 64 + lane] = enc_fp8_pair(f0, f1);
#pragma unroll
    for (int h = 0; h < NH; ++h) {
        float ps = f0 * vS[h * DIM + c] + f1 * vS[h * DIM + c + 1];
        float pd = f0 * vD[h * DIM + c] + f1 * vD[h * DIM + c + 1];
#pragma unroll
        for (int msk = 1; msk < 64; msk <<= 1) {
            ps += __shfl_xor(ps, msk);
            pd += __shfl_xor(pd, msk);
        }
        if (lane == 0) {
            a_s[n * 4 + h] = ps;
            a_d[n * 4 + h] = pd;
        }
    }
}

// GAT gather for one node, one wave; wshw/sshw = this wave's private LDS slots (64 entries)
__device__ __forceinline__ void gather_node(int n, int lane,
        float4* wshw, int* sshw,
        const int* __restrict__ row_ptr, const int* __restrict__ csr_src,
        const float* __restrict__ a_s, const float* __restrict__ a_d,
        const unsigned short* __restrict__ x8, bf16_t* __restrict__ y) {
    int beg = row_ptr[n];
    int deg = row_ptr[n + 1] - beg;
    if (deg < 0) deg = 0;
    if (deg > NEDGE) deg = NEDGE;
    if (beg < 0) beg = 0;
    if (beg > NEDGE - deg) beg = NEDGE - deg;

    const float4* a_s4 = reinterpret_cast<const float4*>(a_s);
    const float4 adv = reinterpret_cast<const float4*>(a_d)[n];
    const float4 avs = a_s4[n];
    unsigned short pself = x8[n * 64 + lane];
    float4 wself = {__expf(leaky(avs.x + adv.x)), __expf(leaky(avs.y + adv.y)),
                    __expf(leaky(avs.z + adv.z)), __expf(leaky(avs.w + adv.w))};

    float acc[8];
    {
        f32v2 f = __builtin_amdgcn_cvt_pk_f32_fp8((int)pself, false);
        acc[0] = wself.x * f[0]; acc[1] = wself.x * f[1];
        acc[2] = wself.y * f[0]; acc[3] = wself.y * f[1];
        acc[4] = wself.z * f[0]; acc[5] = wself.z * f[1];
        acc[6] = wself.w * f[0]; acc[7] = wself.w * f[1];
    }

    float4 zl = {0.f, 0.f, 0.f, 0.f};
    for (int c0 = 0; c0 < deg; c0 += 64) {
        int cnt = deg - c0; if (cnt > 64) cnt = 64;
        if (lane < cnt) {
            int s = clamp_node(csr_src[beg + c0 + lane]);
            float4 av = a_s4[s];
            float4 w = {__expf(leaky(av.x + adv.x)), __expf(leaky(av.y + adv.y)),
                        __expf(leaky(av.z + adv.z)), __expf(leaky(av.w + adv.w))};
            zl.x += w.x; zl.y += w.y; zl.z += w.z; zl.w += w.w;
            wshw[lane] = w;
            sshw[lane] = s << 6;
        }
        for (int u0 = 0; u0 < cnt; u0 += 8) {
            int uc = cnt - u0; if (uc > 8) uc = 8;
            unsigned short xe[8]; float4 w[8];
#pragma unroll
            for (int u = 0; u < 8; ++u) {
                if (u < uc) {
                    int sb = sshw[u0 + u];     // uniform address -> broadcast
                    w[u] = wshw[u0 + u];
                    xe[u] = x8[sb + lane];
                }
            }
#pragma unroll
            for (int u = 0; u < 8; ++u) {
                if (u < uc) {
                    f32v2 f = __builtin_amdgcn_cvt_pk_f32_fp8((int)xe[u], false);
                    acc[0] += w[u].x * f[0]; acc[1] += w[u].x * f[1];
                    acc[2] += w[u].y * f[0]; acc[3] += w[u].y * f[1];
                    acc[4] += w[u].z * f[0]; acc[5] += w[u].z * f[1];
                    acc[6] += w[u].w * f[0]; acc[7] += w[u].w * f[1];
                }
            }
        }
    }
    float4 zr = zl;
#pragma unroll
    for (int msk = 1; msk < 64; msk <<= 1) {
        zr.x += __shfl_xor(zr.x, msk);
        zr.y += __shfl_xor(zr.y, msk);
        zr.z += __shfl_xor(zr.z, msk);
        zr.w += __shfl_xor(zr.w, msk);
    }
    float4 z4 = {wself.x + zr.x, wself.y + zr.y, wself.z + zr.z, wself.w + zr.w};
    float4 ih4 = {1.f / z4.x, 1.f / z4.y, 1.f / z4.z, 1.f / z4.w};
    int c = 2 * lane;
#pragma unroll
    for (int h = 0; h < NH; ++h) {
        float ih = h == 0 ? ih4.x : h == 1 ? ih4.y : h == 2 ? ih4.z : ih4.w;
        bf16v2 o;
        o[0] = (bf16_t)(acc[h * 2 + 0] * ih);
        o[1] = (bf16_t)(acc[h * 2 + 1] * ih);
        *reinterpret_cast<bf16v2*>(&y[(size_t)n * HD + h * DIM + c]) = o;
    }
}

// mix+FFN for one 16-node tile. last=false: writes bf16 xb + next-layer x8/a_s/a_d;
// last=true: writes f32 out.  NOTE: xb and out may alias (no __restrict__ on them).
__device__ __forceinline__ void mix_tile(char* smem, int tile, bool last,
        const bf16_t* __restrict__ y,
        const bf16_t* __restrict__ WmixP, const bf16_t* __restrict__ bg,
        const bf16_t* __restrict__ n1w, const bf16_t* xb,
        const bf16_t* __restrict__ W1P, const bf16_t* __restrict__ b1,
        const bf16_t* __restrict__ W2P, const bf16_t* __restrict__ b2,
        const bf16_t* __restrict__ n2w, void* out,
        const float* __restrict__ vS, const float* __restrict__ vD,
        float* __restrict__ a_s_n, float* __restrict__ a_d_n,
        unsigned char* __restrict__ x8_n) {
    bf16_t (*ylds)[524]    = reinterpret_cast<bf16_t(*)[524]>(smem);
    bf16_t (*xm)[140]      = reinterpret_cast<bf16_t(*)[140]>(smem + 16768);
    float  (*ssq_p)[4]     = reinterpret_cast<float(*)[4]>(smem + 21248);
    float  (*asd_p)[16][8] = reinterpret_cast<float(*)[16][8]>(smem + 21504);
    bf16_t (*hh)[140]      = reinterpret_cast<bf16_t(*)[140]>(smem);   // alias ylds

    int wv = (int)threadIdx.x >> 6;
    int lane = (int)threadIdx.x & 63;
    int m = lane & 15, kq = lane >> 4;

    const bf16_t* ybase = y + (size_t)tile * 16 * HD;
#pragma unroll
    for (int it = 0; it < 8; ++it) {
        int f = it * 2048 + (int)threadIdx.x * 8;
        int row = f >> 9, col = f & 511;
        *reinterpret_cast<bf16v8*>(&ylds[row][col]) =
            *reinterpret_cast<const bf16v8*>(ybase + f);
    }
    __syncthreads();

    f32v4 accm[2];
    accm[0] = (f32v4){0.f, 0.f, 0.f, 0.f};
    accm[1] = (f32v4){0.f, 0.f, 0.f, 0.f};
#pragma unroll
    for (int kk = 0; kk < 16; ++kk) {
        bf16v8 a = *reinterpret_cast<const bf16v8*>(&ylds[m][kk * 32 + kq * 8]);
#pragma unroll
        for (int tt = 0; tt < 2; ++tt) {
            bf16v8 b = *reinterpret_cast<const bf16v8*>(
                WmixP + ((((wv * 16 + kk) * 2 + tt) << 9) + lane * 8));
            accm[tt] = __builtin_amdgcn_mfma_f32_16x16x32_bf16(a, b, accm[tt], 0, 0, 0);
        }
    }
    float vals[2][4];
    {
        float sp[4] = {0.f, 0.f, 0.f, 0.f};
#pragma unroll
        for (int tt = 0; tt < 2; ++tt) {
            int col = 32 * wv + tt * 16 + m;
            float bv = (float)bg[col];
#pragma unroll
            for (int r = 0; r < 4; ++r) {
                int gr = tile * 16 + kq * 4 + r;
                float v = 0.25f * accm[tt][r] + bv + (float)xb[(size_t)gr * DIM + col];
                vals[tt][r] = v;
                sp[r] += v * v;
            }
        }
#pragma unroll
        for (int r = 0; r < 4; ++r) {
            sp[r] += __shfl_xor(sp[r], 1); sp[r] += __shfl_xor(sp[r], 2);
            sp[r] += __shfl_xor(sp[r], 4); sp[r] += __shfl_xor(sp[r], 8);
            if (m == r) ssq_p[kq * 4 + r][wv] = sp[r];
        }
    }
    __syncthreads();
    {
#pragma unroll
        for (int r = 0; r < 4; ++r) {
            int row = kq * 4 + r;
            float s = ssq_p[row][0] + ssq_p[row][1] + ssq_p[row][2] + ssq_p[row][3];
            float scale = rsqrtf(s * (1.f / 128.f) + EPS_RMS);
#pragma unroll
            for (int tt = 0; tt < 2; ++tt) {
                int col = 32 * wv + tt * 16 + m;
                xm[row][col] = (bf16_t)(vals[tt][r] * scale * (float)n1w[col]);
            }
        }
    }
    __syncthreads();

    f32v4 acc1[2];
    acc1[0] = (f32v4){0.f, 0.f, 0.f, 0.f};
    acc1[1] = (f32v4){0.f, 0.f, 0.f, 0.f};
#pragma unroll
    for (int ks = 0; ks < 4; ++ks) {
        bf16v8 a = *reinterpret_cast<const bf16v8*>(&xm[m][ks * 32 + kq * 8]);
#pragma unroll
        for (int tt = 0; tt < 2; ++tt) {
            bf16v8 b = *reinterpret_cast<const bf16v8*>(
                W1P + ((((wv * 4 + ks) * 2 + tt) << 9) + lane * 8));
            acc1[tt] = __builtin_amdgcn_mfma_f32_16x16x32_bf16(a, b, acc1[tt], 0, 0, 0);
        }
    }
#pragma unroll
    for (int tt = 0; tt < 2; ++tt) {
        int col = 32 * wv + tt * 16 + m;
        float bv = (float)b1[col];
#pragma unroll
        for (int r = 0; r < 4; ++r) {
            float v = acc1[tt][r] + bv;
            hh[kq * 4 + r][col] = (bf16_t)(v > 0.f ? v : 0.f);
        }
    }
    __syncthreads();
    f32v4 acc2[2];
    acc2[0] = (f32v4){0.f, 0.f, 0.f, 0.f};
    acc2[1] = (f32v4){0.f, 0.f, 0.f, 0.f};
#pragma unroll
    for (int ks = 0; ks < 4; ++ks) {
        bf16v8 a = *reinterpret_cast<const bf16v8*>(&hh[m][ks * 32 + kq * 8]);
#pragma unroll
        for (int tt = 0; tt < 2; ++tt) {
            bf16v8 b = *reinterpret_cast<const bf16v8*>(
                W2P + ((((wv * 4 + ks) * 2 + tt) << 9) + lane * 8));
            acc2[tt] = __builtin_amdgcn_mfma_f32_16x16x32_bf16(a, b, acc2[tt], 0, 0, 0);
        }
    }
    float vals2[2][4];
    {
        float sp[4] = {0.f, 0.f, 0.f, 0.f};
#pragma unroll
        for (int tt = 0; tt < 2; ++tt) {
            int col = 32 * wv + tt * 16 + m;
            float bv = (float)b2[col];
#pragma unroll
            for (int r = 0; r < 4; ++r) {
                float v = acc2[tt][r] + bv + (float)xm[kq * 4 + r][col];
                vals2[tt][r] = v;
                sp[r] += v * v;
            }
        }
#pragma unroll
        for (int r = 0; r < 4; ++r) {
            sp[r] += __shfl_xor(sp[r], 1); sp[r] += __shfl_xor(sp[r], 2);
            sp[r] += __shfl_xor(sp[r], 4); sp[r] += __shfl_xor(sp[r], 8);
            if (m == r) ssq_p[kq * 4 + r][wv] = sp[r];
        }
    }
    __syncthreads();
    float o2[2][4];
#pragma unroll
    for (int r = 0; r < 4; ++r) {
        int row = kq * 4 + r;
        int gr = tile * 16 + row;
        float s = ssq_p[row][0] + ssq_p[row][1] + ssq_p[row][2] + ssq_p[row][3];
        float scale = rsqrtf(s * (1.f / 128.f) + EPS_RMS);
#pragma unroll
        for (int tt = 0; tt < 2; ++tt) {
            int col = 32 * wv + tt * 16 + m;
            float o = vals2[tt][r] * scale * (float)n2w[col];
            o2[tt][r] = o;
            if (last) ((float*)out)[(size_t)gr * DIM + col] = o;
            else {
                ((bf16_t*)out)[(size_t)gr * DIM + col] = (bf16_t)o;
                x8_n[(size_t)gr * DIM + col] = enc_fp8(o);
            }
        }
    }
    if (!last) {
        float vs0[NH], vs1[NH], vd0[NH], vd1[NH];
        int col0 = 32 * wv + m, col1 = col0 + 16;
#pragma unroll
        for (int h = 0; h < NH; ++h) {
            vs0[h] = vS[h * DIM + col0]; vs1[h] = vS[h * DIM + col1];
            vd0[h] = vD[h * DIM + col0]; vd1[h] = vD[h * DIM + col1];
        }
#pragma unroll
        for (int r = 0; r < 4; ++r) {
#pragma unroll
            for (int h = 0; h < NH; ++h) {
                float ps = o2[0][r] * vs0[h] + o2[1][r] * vs1[h];
                float pd = o2[0][r] * vd0[h] + o2[1][r] * vd1[h];
                ps += __shfl_xor(ps, 1); ps += __shfl_xor(ps, 2);
                ps += __shfl_xor(ps, 4); ps += __shfl_xor(ps, 8);
                pd += __shfl_xor(pd, 1); pd += __shfl_xor(pd, 2);
                pd += __shfl_xor(pd, 4); pd += __shfl_xor(pd, 8);
                if (m == r * 4 + h) {
                    asd_p[wv][kq * 4 + r][h * 2 + 0] = ps;
                    asd_p[wv][kq * 4 + r][h * 2 + 1] = pd;
                }
            }
        }
        __syncthreads();
        int t = threadIdx.x;
        if (t < 128) {
            int row = t >> 3, idx = t & 7;
            float s = asd_p[0][row][idx] + asd_p[1][row][idx]
                    + asd_p[2][row][idx] + asd_p[3][row][idx];
            int gr = tile * 16 + row;
            if (idx & 1) a_d_n[gr * 4 + (idx >> 1)] = s;
            else         a_s_n[gr * 4 + (idx >> 1)] = s;
        }
    }
}

// ================= fused cooperative kernel =================
struct Params {
    const void *x, *Wg, *aS, *aD, *bg, *W1, *b1, *W2, *b2, *n1, *n2;
    const int* ei;
    bf16_t *WmixP, *W1P, *W2P, *xb, *y;
    unsigned short *x8a, *x8b;
    float *vS, *vD;
    float *a_sA, *a_dA, *a_sB, *a_dB;
    int *deg, *cursor, *row_ptr, *csr;
    bf16_t *bgc, *b1c, *b2c, *n1c, *n2c;
    void* out;
};

__global__ __launch_bounds__(256, 4) void fused_all(Params p) {
    __shared__ __align__(16) char smem[SMEM_BYTES];
    cg::grid_group grid = cg::this_grid();
    const int NBLK  = (int)gridDim.x;
    const int NTH   = NBLK * 256;
    const int NWAVE = NBLK * 4;
    int b = (int)blockIdx.x, t = (int)threadIdx.x;
    int wv = t >> 6, lane = t & 63;
    int gtid = b * 256 + t;
    int gwave = b * 4 + wv;
    bool isbf = wave_detect_bf16((const unsigned short*)p.x);
    bool is64 = wave_detect_i64(p.ei);

    // ---------- P0: deg zero + prep_v + xb vec-convert ----------
    for (int i = gtid; i < N_NODES; i += NTH) p.deg[i] = 0;
    for (int w = gwave; w < LAYERS * DIM * NH * 2; w += NWAVE) {
        int sd = w & 1, h = (w >> 1) & 3, k = (w >> 3) & 127, l = w >> 10;
        const void* att = sd ? p.aD : p.aS;
        size_t wbase = (size_t)l * DIM * HD + (size_t)k * HD + h * DIM;
        size_t abase = (size_t)l * NH * DIM + (size_t)h * DIM;
        int c = 2 * lane;
        float pr = raw_elem(p.Wg, wbase + c, isbf) * raw_elem(att, abase + c, isbf)
                 + raw_elem(p.Wg, wbase + c + 1, isbf) * raw_elem(att, abase + c + 1, isbf);
#pragma unroll
        for (int msk = 1; msk < 64; msk <<= 1) pr += __shfl_xor(pr, msk);
        if (lane == 0) (sd ? p.vD : p.vS)[l * HD + h * DIM + k] = pr;
    }
    {
        const int NV8 = N_NODES * DIM / 8;
        if (isbf) {
            const bf16v8* src = (const bf16v8*)p.x;
            bf16v8* dst = (bf16v8*)p.xb;
            for (int i = gtid; i < NV8; i += NTH) dst[i] = src[i];
        } else {
            const float4* src = (const float4*)p.x;
            bf16v8* dst = (bf16v8*)p.xb;
            for (int i = gtid; i < NV8; i += NTH) {
                float4 a = src[2 * i], bq = src[2 * i + 1];
                bf16v8 o;
                o[0] = (bf16_t)a.x;  o[1] = (bf16_t)a.y;
                o[2] = (bf16_t)a.z;  o[3] = (bf16_t)a.w;
                o[4] = (bf16_t)bq.x; o[5] = (bf16_t)bq.y;
                o[6] = (bf16_t)bq.z; o[7] = (bf16_t)bq.w;
                dst[i] = o;
            }
        }
    }
    grid.sync();

    // ---------- P1: hist | asd_x8 | weight pack (block-range split) ----------
    {
        int histB = NBLK >> 3;
        int asdB  = NBLK >> 2;
        if (b < histB) {
            for (int e = b * 256 + t; e < NEDGE; e += histB * 256)
                atomicAdd(&p.deg[edge_dst(p.ei, e, is64)], 1);
        } else if (b < histB + asdB) {
            int aw = (b - histB) * 4 + wv;
            int astr = asdB * 4;
            for (int n = aw; n < N_NODES; n += astr)
                asd_node(n, lane, isbf, p.x, p.vS, p.vD, p.a_sA, p.a_dA, p.x8a);
        } else {
            int packB = NBLK - histB - asdB;
            int pstr = packB * 256;
            for (int i = (b - histB - asdB) * 256 + t; i < NPACK; i += pstr)
                pack_item(i, isbf, p.Wg, p.W1, p.W2, p.bg, p.b1, p.b2, p.n1, p.n2,
                          p.WmixP, p.W1P, p.W2P, p.bgc, p.b1c, p.b2c, p.n1c, p.n2c);
        }
    }
    grid.sync();

    // ---------- P2: scan (block 0 only, chunk=80/thread, 2-pass) ----------
    if (b == 0) {
        int* wsum = (int*)smem;
        int base = t * 80;
        int tot = 0;
        if (base < N_NODES) {
            const int4* d4 = (const int4*)(p.deg + base);
#pragma unroll
            for (int j = 0; j < 20; ++j) {
                int4 q = d4[j];
                tot += q.x + q.y + q.z + q.w;
            }
        }
        int x = tot;
#pragma unroll
        for (int off = 1; off < 64; off <<= 1) {
            int tv = __shfl_up(x, off);
            if (lane >= off) x += tv;
        }
        if (lane == 63) wsum[wv] = x;
        __syncthreads();
        int woff = 0;
        for (int j = 0; j < wv; ++j) woff += wsum[j];
        int run = woff + (x - tot);
        if (t == 0) p.row_ptr[0] = 0;
        if (base < N_NODES) {
            const int4* d4 = (const int4*)(p.deg + base);
#pragma unroll
            for (int j = 0; j < 20; ++j) {
                int4 q = d4[j];
                int n = base + 4 * j;
                p.cursor[n] = run;     run += q.x; p.row_ptr[n + 1] = run;
                p.cursor[n + 1] = run; run += q.y; p.row_ptr[n + 2] = run;
                p.cursor[n + 2] = run; run += q.z; p.row_ptr[n + 3] = run;
                p.cursor[n + 3] = run; run += q.w; p.row_ptr[n + 4] = run;
            }
        }
    }
    grid.sync();

    // ---------- P3: fill ----------
    for (int e = gtid; e < NEDGE; e += NTH) {
        int d = edge_dst(p.ei, e, is64);
        int pos = atomicAdd(&p.cursor[d], 1);
        if ((unsigned)pos < (unsigned)NEDGE) p.csr[pos] = edge_src(p.ei, e, is64);
    }
    grid.sync();

    // ---------- layers ----------
    unsigned short* x8cur[2] = {p.x8a, p.x8b};
    float* asCur[2] = {p.a_sA, p.a_sB};
    float* adCur[2] = {p.a_dA, p.a_dB};
#pragma unroll
    for (int l = 0; l < LAYERS; ++l) {
        int ci = l & 1, ni = (l + 1) & 1;
        {
            float4* wshw = (float4*)smem + wv * 64;
            int* sshw = (int*)(smem + 4096) + wv * 64;
            for (int n = gwave; n < N_NODES; n += NWAVE)
                gather_node(n, lane, wshw, sshw, p.row_ptr, p.csr,
                            asCur[ci], adCur[ci], x8cur[ci], p.y);
        }
        grid.sync();
        bool last = (l == LAYERS - 1);
        for (int tile = b; tile < NTILES; tile += NBLK) {
            mix_tile(smem, tile, last,
                     p.y, p.WmixP + (size_t)l * HD * DIM, p.bgc + l * DIM,
                     p.n1c + l * DIM, p.xb,
                     p.W1P + (size_t)l * DIM * DIM, p.b1c + l * DIM,
                     p.W2P + (size_t)l * DIM * DIM, p.b2c + l * DIM,
                     p.n2c + l * DIM, last ? p.out : (void*)p.xb,
                     p.vS + (size_t)(l + 1) * HD, p.vD + (size_t)(l + 1) * HD,
                     asCur[ni], adCur[ni], (unsigned char*)x8cur[ni]);
        }
        if (!last) grid.sync();
    }
}

// ================= fallback multi-dispatch kernels =================

__global__ __launch_bounds__(256) void prep_v(const void* x, const void* Wg,
                                              const void* aS, const void* aD,
                                              float* __restrict__ vS, float* __restrict__ vD,
                                              int* __restrict__ deg) {
    int gid = blockIdx.x * 256 + threadIdx.x;
    for (int i = gid; i < N_NODES; i += gridDim.x * 256) deg[i] = 0;
    bool isbf = wave_detect_bf16((const unsigned short*)x);
    int w = gid >> 6;
    if (w >= LAYERS * DIM * NH * 2) return;
    int lane = threadIdx.x & 63;
    int sd = w & 1, h = (w >> 1) & 3, k = (w >> 3) & 127, l = w >> 10;
    const void* att = sd ? aD : aS;
    size_t wbase = (size_t)l * DIM * HD + (size_t)k * HD + h * DIM;
    size_t abase = (size_t)l * NH * DIM + (size_t)h * DIM;
    int c = 2 * lane;
    float p = raw_elem(Wg, wbase + c, isbf) * raw_elem(att, abase + c, isbf)
            + raw_elem(Wg, wbase + c + 1, isbf) * raw_elem(att, abase + c + 1, isbf);
#pragma unroll
    for (int msk = 1; msk < 64; msk <<= 1) p += __shfl_xor(p, msk);
    if (lane == 0) {
        float* dst = sd ? vD : vS;
        dst[l * HD + h * DIM + k] = p;
    }
}

__global__ __launch_bounds__(256) void mega_setup(
        const void* x, const void* Wg, const void* W1, const void* W2,
        const void* bg, const void* b1, const void* b2, const void* n1, const void* n2,
        bf16_t* xb, bf16_t* WmixP, bf16_t* W1P, bf16_t* W2P,
        bf16_t* bgc, bf16_t* b1c, bf16_t* b2c, bf16_t* n1c, bf16_t* n2c,
        const int* ei, int* deg,
        const float* vS, const float* vD,
        float* a_s, float* a_d, unsigned short* x8,
        int convBlocks, int histBlocks) {
    const int NX = N_NODES * DIM;
    int b = (int)blockIdx.x;
    if (b >= convBlocks + histBlocks) {
        bool isbf = wave_detect_bf16((const unsigned short*)x);
        int lane = threadIdx.x & 63;
        int n = (b - convBlocks - histBlocks) * 4 + (int)(threadIdx.x >> 6);
        if (n >= N_NODES) return;
        asd_node(n, lane, isbf, x, vS, vD, a_s, a_d, x8);
        return;
    }
    if (b >= convBlocks) {
        bool is64 = wave_detect_i64(ei);
        int e = (b - convBlocks) * 256 + threadIdx.x;
        if (e < NEDGE) atomicAdd(&deg[edge_dst(ei, e, is64)], 1);
        return;
    }
    bool isbf = wave_detect_bf16((const unsigned short*)x);
    int i = b * 256 + threadIdx.x;
    if (i < NX) { xb[i] = cvt_elem(x, i, isbf); return; }
    pack_item(i - NX, isbf, Wg, W1, W2, bg, b1, b2, n1, n2,
              WmixP, W1P, W2P, bgc, b1c, b2c, n1c, n2c);
}

__global__ __launch_bounds__(1024) void scan_kernel(const int* __restrict__ deg,
                                                    int* __restrict__ row_ptr,
                                                    int* __restrict__ cursor) {
    __shared__ int wsum[16];
    int tid = threadIdx.x, lane = tid & 63, wv = tid >> 6;
    int v[20];
    int base = tid * 20;
    int tot = 0;
    if (base < N_NODES) {
        const int4* d4 = reinterpret_cast<const int4*>(deg + base);
#pragma unroll
        for (int j = 0; j < 5; ++j) {
            int4 q = d4[j];
            v[4 * j]     = q.x;
            v[4 * j + 1] = q.y;
            v[4 * j + 2] = q.z;
            v[4 * j + 3] = q.w;
        }
#pragma unroll
        for (int i = 0; i < 20; ++i) tot += v[i];
    }
    int x = tot;
#pragma unroll
    for (int off = 1; off < 64; off <<= 1) {
        int t = __shfl_up(x, off);
        if (lane >= off) x += t;
    }
    if (lane == 63) wsum[wv] = x;
    __syncthreads();
    if (wv == 0) {
        int s = (lane < 16) ? wsum[lane] : 0;
#pragma unroll
        for (int off = 1; off < 16; off <<= 1) {
            int t = __shfl_up(s, off);
            if (lane >= off) s += t;
        }
        if (lane < 16) wsum[lane] = s;
    }
    __syncthreads();
    int off0 = ((wv == 0) ? 0 : wsum[wv - 1]) + (x - tot);
    if (tid == 0) row_ptr[0] = 0;
    if (base < N_NODES) {
        int run = off0;
#pragma unroll
        for (int i = 0; i < 20; ++i) {
            run += v[i];
            row_ptr[base + i + 1] = run;
            cursor[base + i] = run - v[i];
        }
    }
}

__global__ void fill_kernel(const int* __restrict__ ei, int* __restrict__ cursor,
                            int* __restrict__ csr_src) {
    bool is64 = wave_detect_i64(ei);
    int e = blockIdx.x * blockDim.x + threadIdx.x;
    if (e < NEDGE) {
        int d = edge_dst(ei, e, is64);
        int pos = atomicAdd(&cursor[d], 1);
        if ((unsigned)pos < (unsigned)NEDGE) csr_src[pos] = edge_src(ei, e, is64);
    }
}

__global__ __launch_bounds__(256) void gat_gather(const int* __restrict__ row_ptr,
                                                  const int* __restrict__ csr_src,
                                                  const float* __restrict__ a_s,
                                                  const float* __restrict__ a_d,
                                                  const unsigned short* __restrict__ x8,
                                                  bf16_t* __restrict__ y) {
    __shared__ float4 wsh[4][64];
    __shared__ int    ssh[4][64];
    int n = (int)((blockIdx.x * blockDim.x + threadIdx.x) >> 6);
    if (n >= N_NODES) return;
    int wv = (int)(threadIdx.x >> 6) & 3;
    int lane = threadIdx.x & 63;
    gather_node(n, lane, wsh[wv], ssh[wv], row_ptr, csr_src, a_s, a_d, x8, y);
}

template <int MODE>
__global__ __launch_bounds__(256) void mix_ffn(
        const bf16_t* __restrict__ y,
        const bf16_t* __restrict__ WmixP, const bf16_t* __restrict__ bg,
        const bf16_t* __restrict__ n1w, const bf16_t* xb,
        const bf16_t* __restrict__ W1P, const bf16_t* __restrict__ b1,
        const bf16_t* __restrict__ W2P, const bf16_t* __restrict__ b2,
        const bf16_t* __restrict__ n2w, void* out,
        const float* __restrict__ vS, const float* __restrict__ vD,
        float* __restrict__ a_s_n, float* __restrict__ a_d_n,
        unsigned char* __restrict__ x8_n) {
    __shared__ __align__(16) char smem[SMEM_BYTES];
    mix_tile(smem, (int)blockIdx.x, MODE == 1, y, WmixP, bg, n1w, xb,
             W1P, b1, W2P, b2, n2w, out, vS, vD, a_s_n, a_d_n, x8_n);
}

// ================= launch =================
extern "C" void kernel_launch(void* const* d_in, const int* in_sizes, int n_in,
                              void* d_out, int out_size, void* d_ws, size_t ws_size,
                              hipStream_t stream) {
    const void* x_in   = d_in[0];
    const void* W_gat  = d_in[1];
    const void* att_s  = d_in[2];
    const void* att_d  = d_in[3];
    const void* bias_g = d_in[4];
    const void* W1     = d_in[5];
    const void* b1     = d_in[6];
    const void* W2     = d_in[7];
    const void* b2     = d_in[8];
    const void* n1w    = d_in[9];
    const void* n2w    = d_in[10];
    const int*  ei     = (const int*)d_in[11];

    char* ws = (char*)d_ws;
    size_t off = 0;
    auto alloc = [&](size_t bytes) {
        void* p = ws + off;
        off = (off + bytes + 255) & ~(size_t)255;
        return p;
    };
    bf16_t* WmixP   = (bf16_t*)alloc((size_t)LAYERS * HD * DIM * 2);
    bf16_t* W1P     = (bf16_t*)alloc((size_t)LAYERS * DIM * DIM * 2);
    bf16_t* W2P     = (bf16_t*)alloc((size_t)LAYERS * DIM * DIM * 2);
    bf16_t* xb      = (bf16_t*)alloc((size_t)N_NODES * DIM * 2);
    bf16_t* y       = (bf16_t*)alloc((size_t)N_NODES * HD * 2);
    unsigned short* x8a = (unsigned short*)alloc((size_t)N_NODES * DIM);
    unsigned short* x8b = (unsigned short*)alloc((size_t)N_NODES * DIM);
    float*  vS      = (float*)alloc((size_t)LAYERS * HD * 4);
    float*  vD      = (float*)alloc((size_t)LAYERS * HD * 4);
    float*  a_sA    = (float*)alloc((size_t)N_NODES * NH * 4);
    float*  a_dA    = (float*)alloc((size_t)N_NODES * NH * 4);
    float*  a_sB    = (float*)alloc((size_t)N_NODES * NH * 4);
    float*  a_dB    = (float*)alloc((size_t)N_NODES * NH * 4);
    int*    deg     = (int*)alloc((size_t)N_NODES * 4);
    int*    cursor  = (int*)alloc((size_t)N_NODES * 4);
    int*    row_ptr = (int*)alloc((size_t)(N_NODES + 1) * 4);
    int*    csr     = (int*)alloc((size_t)NEDGE * 4);
    bf16_t* bgc     = (bf16_t*)alloc((size_t)LAYERS * DIM * 2);
    bf16_t* b1c     = (bf16_t*)alloc((size_t)LAYERS * DIM * 2);
    bf16_t* b2c     = (bf16_t*)alloc((size_t)LAYERS * DIM * 2);
    bf16_t* n1c     = (bf16_t*)alloc((size_t)LAYERS * DIM * 2);
    bf16_t* n2c     = (bf16_t*)alloc((size_t)LAYERS * DIM * 2);

    // ---- cooperative grid sizing (computed once) ----
    static int coopBlocks = -1;
    if (coopBlocks == -1) {
        int perCU = 0;
        int nCU = 256;
        hipDeviceProp_t prop;
        int dev = 0;
        if (hipGetDevice(&dev) == hipSuccess &&
            hipGetDeviceProperties(&prop, dev) == hipSuccess)
            nCU = prop.multiProcessorCount;
        if (hipOccupancyMaxActiveBlocksPerMultiprocessor(
                &perCU, reinterpret_cast<const void*>(fused_all), 256, 0) != hipSuccess)
            perCU = 0;
        long cap = (long)perCU * nCU;
        coopBlocks = (cap >= 8) ? (int)(cap < 1024 ? cap : 1024) : 0;
    }

    bool done = false;
    if (coopBlocks >= 8) {
        Params prm;
        prm.x = x_in; prm.Wg = W_gat; prm.aS = att_s; prm.aD = att_d;
        prm.bg = bias_g; prm.W1 = W1; prm.b1 = b1; prm.W2 = W2; prm.b2 = b2;
        prm.n1 = n1w; prm.n2 = n2w; prm.ei = ei;
        prm.WmixP = WmixP; prm.W1P = W1P; prm.W2P = W2P; prm.xb = xb; prm.y = y;
        prm.x8a = x8a; prm.x8b = x8b; prm.vS = vS; prm.vD = vD;
        prm.a_sA = a_sA; prm.a_dA = a_dA; prm.a_sB = a_sB; prm.a_dB = a_dB;
        prm.deg = deg; prm.cursor = cursor; prm.row_ptr = row_ptr; prm.csr = csr;
        prm.bgc = bgc; prm.b1c = b1c; prm.b2c = b2c; prm.n1c = n1c; prm.n2c = n2c;
        prm.out = d_out;
        void* kargs[] = {(void*)&prm};
        hipError_t err = hipLaunchCooperativeKernel(
            reinterpret_cast<const void*>(fused_all),
            dim3(coopBlocks), dim3(256), kargs, 0, stream);
        if (err == hipSuccess) done = true;
        else { (void)hipGetLastError(); coopBlocks = 0; }
    }

    if (!done) {   // fallback: proven 10-dispatch path
        prep_v<<<(LAYERS * DIM * NH * 2 * 64 + 255) / 256, 256, 0, stream>>>(
            x_in, W_gat, att_s, att_d, vS, vD, deg);

        const int NTOT = N_NODES * DIM + NPACK;
        const int convBlocks = (NTOT + 255) / 256;
        const int histBlocks = (NEDGE + 255) / 256;
        const int asdBlocks  = (N_NODES + 3) / 4;
        mega_setup<<<convBlocks + histBlocks + asdBlocks, 256, 0, stream>>>(
            x_in, W_gat, W1, W2, bias_g, b1, b2, n1w, n2w,
            xb, WmixP, W1P, W2P, bgc, b1c, b2c, n1c, n2c,
            ei, deg, vS, vD, a_sA, a_dA, x8a, convBlocks, histBlocks);

        scan_kernel<<<1, 1024, 0, stream>>>(deg, row_ptr, cursor);
        fill_kernel<<<(NEDGE + 255) / 256, 256, 0, stream>>>(ei, cursor, csr);

        unsigned short* x8cur[2] = {x8a, x8b};
        float* asCur[2] = {a_sA, a_sB};
        float* adCur[2] = {a_dA, a_dB};
        for (int l = 0; l < LAYERS; ++l) {
            int ci = l & 1, ni = (l + 1) & 1;
            gat_gather<<<(N_NODES * 64 + 255) / 256, 256, 0, stream>>>(
                row_ptr, csr, asCur[ci], adCur[ci], x8cur[ci], y);
            if (l < LAYERS - 1) {
                mix_ffn<0><<<NTILES, 256, 0, stream>>>(
                    y, WmixP + (size_t)l * HD * DIM, bgc + (size_t)l * DIM,
                    n1c + (size_t)l * DIM, xb,
                    W1P + (size_t)l * DIM * DIM, b1c + (size_t)l * DIM,
                    W2P + (size_t)l * DIM * DIM, b2c + (size_t)l * DIM,
                    n2c + (size_t)l * DIM, xb,
                    vS + (size_t)(l + 1) * HD, vD + (size_t)(l + 1) * HD,
                    asCur[ni], adCur[ni], (unsigned char*)x8cur[ni]);
            } else {
                mix_ffn<1><<<NTILES, 256, 0, stream>>>(
                    y, WmixP + (size_t)l * HD * DIM, bgc + (size_t)l * DIM,
                    n1c + (size_t)l * DIM, xb,
                    W1P + (size_t)l * DIM * DIM, b1c + (size_t)l * DIM,
                    W2P + (size_t)l * DIM * DIM, b2c + (size_t)l * DIM,
                    n2c + (size_t)l * DIM, d_out,
                    nullptr, nullptr, nullptr, nullptr, nullptr);
            }
        }
    }
}

// Round 3
// 300.966 us; speedup vs baseline: 3.4717x; 3.4717x over previous
//
#include <hip/hip_runtime.h>
#include <hip/hip_bf16.h>

#define N_NODES 20000
#define NEDGE   320000
#define DIM     128
#define NH      4
#define HD      512   // NH*DIM
#define LAYERS  3
#define EPS_RMS 1.1920929e-07f
#define SLOPE   0.2f
#define NTILES  (N_NODES >> 4)   // 1250

#define NWGC  (LAYERS * DIM * HD)    // 196608
#define NW1C  (LAYERS * DIM * DIM)   // 49152
#define NVC   (LAYERS * DIM)         // 384
#define NPACK (NWGC + 2 * NW1C + 5 * NVC)   // 296832
#define NXV   (N_NODES * DIM / 8)    // 320000 vec8 items

typedef __bf16 bf16_t;
typedef __bf16 bf16v2 __attribute__((ext_vector_type(2)));
typedef __bf16 bf16v8 __attribute__((ext_vector_type(8)));
typedef float  f32v4  __attribute__((ext_vector_type(4)));
typedef float  f32v2  __attribute__((ext_vector_type(2)));

__device__ __forceinline__ int clamp_node(int s) {
    return ((unsigned)s >= (unsigned)N_NODES) ? 0 : s;
}
__device__ __forceinline__ float leaky(float e) { return e > 0.f ? e : SLOPE * e; }
__device__ __forceinline__ unsigned char enc_fp8(float v) {
    int p = __builtin_amdgcn_cvt_pk_fp8_f32(v, v, 0, false);
    return (unsigned char)(p & 0xff);
}
__device__ __forceinline__ unsigned short enc_fp8_pair(float a, float b) {
    int p = __builtin_amdgcn_cvt_pk_fp8_f32(a, b, 0, false);
    return (unsigned short)(p & 0xffff);
}

// ---- per-wave dtype detection ----
__device__ __forceinline__ bool wave_detect_bf16(const unsigned short* xh) {
    int lane = threadIdx.x & 63;
    unsigned short hw = xh[2 * lane];
    int e = (hw >> 7) & 0xff;
    unsigned long long b = __ballot(e >= 96 && e <= 140);
    return __popcll(b) >= 48;
}
__device__ __forceinline__ bool wave_detect_i64(const int* ei) {
    int lane = threadIdx.x & 63;
    unsigned long long b = __ballot(ei[2 * lane + 1] != 0);
    return b == 0ULL;
}
__device__ __forceinline__ float raw_elem(const void* in, size_t j, bool isbf) {
    return isbf ? (float)((const bf16_t*)in)[j] : ((const float*)in)[j];
}
__device__ __forceinline__ bf16_t cvt_elem(const void* in, size_t j, bool isbf) {
    return isbf ? ((const bf16_t*)in)[j] : (bf16_t)((const float*)in)[j];
}
__device__ __forceinline__ int edge_src(const int* ei, int e, bool is64) {
    return clamp_node(is64 ? ei[2 * e] : ei[e]);
}
__device__ __forceinline__ int edge_dst(const int* ei, int e, bool is64) {
    return clamp_node(is64 ? ei[2 * NEDGE + 2 * e] : ei[NEDGE + e]);
}

// ---------------- prep_v (+ deg zeroing): v_s/v_d[l][h][k] = Wg[l][k][h*128+:]·att[l][h][:] ----------------
__global__ __launch_bounds__(256) void prep_v(const void* x, const void* Wg,
                                              const void* aS, const void* aD,
                                              float* __restrict__ vS, float* __restrict__ vD,
                                              int* __restrict__ deg) {
    int gid = blockIdx.x * 256 + threadIdx.x;
    for (int i = gid; i < N_NODES; i += gridDim.x * 256) deg[i] = 0;
    bool isbf = wave_detect_bf16((const unsigned short*)x);
    int w = gid >> 6;
    if (w >= LAYERS * DIM * NH * 2) return;
    int lane = threadIdx.x & 63;
    int sd = w & 1, h = (w >> 1) & 3, k = (w >> 3) & 127, l = w >> 10;
    const void* att = sd ? aD : aS;
    size_t wbase = (size_t)l * DIM * HD + (size_t)k * HD + h * DIM;
    size_t abase = (size_t)l * NH * DIM + (size_t)h * DIM;
    int c = 2 * lane;
    float p = raw_elem(Wg, wbase + c, isbf) * raw_elem(att, abase + c, isbf)
            + raw_elem(Wg, wbase + c + 1, isbf) * raw_elem(att, abase + c + 1, isbf);
#pragma unroll
    for (int msk = 1; msk < 64; msk <<= 1) p += __shfl_xor(p, msk);
    if (lane == 0) {
        float* dst = sd ? vD : vS;
        dst[l * HD + h * DIM + k] = p;
    }
}

// weight fragment-pack + small-vector convert; item space [0, NPACK)
__device__ __forceinline__ void pack_item(int i, bool isbf,
        const void* Wg, const void* W1, const void* W2,
        const void* bg, const void* b1, const void* b2,
        const void* n1, const void* n2,
        bf16_t* WmixP, bf16_t* W1P, bf16_t* W2P,
        bf16_t* bgc, bf16_t* b1c, bf16_t* b2c, bf16_t* n1c, bf16_t* n2c) {
    if (i < NWGC) {   // Wmix fragment-packed
        int l = i >> 16;
        int r = i & 65535;
        int j = r & 7;
        int lane2 = (r >> 3) & 63;
        int mm = lane2 & 15, kqq = lane2 >> 4;
        int tt = (r >> 9) & 1;
        int kk = (r >> 10) & 15;
        int wvv = r >> 14;
        int kidx = kk * 32 + kqq * 8 + j;          // y-dim 0..511
        int h = kidx >> 7, kp = kidx & 127;        // head, source-dim
        int c = 32 * wvv + tt * 16 + mm;           // output col
        WmixP[i] = cvt_elem(Wg, (size_t)l * DIM * HD + (size_t)kp * HD + h * DIM + c, isbf);
        return;
    }
    i -= NWGC;
    if (i < NW1C) {   // W1 fragment-packed
        int l = i / 16384;
        int r = i & 16383;
        int j = r & 7;
        int lane2 = (r >> 3) & 63;
        int mm = lane2 & 15, kqq = lane2 >> 4;
        int tt = (r >> 9) & 1;
        int ks = (r >> 10) & 3;
        int wvv = r >> 12;
        int k = ks * 32 + kqq * 8 + j;
        int c = 32 * wvv + tt * 16 + mm;
        W1P[i] = cvt_elem(W1, (size_t)l * DIM * DIM + (size_t)k * DIM + c, isbf);
        return;
    }
    i -= NW1C;
    if (i < NW1C) {   // W2 fragment-packed
        int l = i / 16384;
        int r = i & 16383;
        int j = r & 7;
        int lane2 = (r >> 3) & 63;
        int mm = lane2 & 15, kqq = lane2 >> 4;
        int tt = (r >> 9) & 1;
        int ks = (r >> 10) & 3;
        int wvv = r >> 12;
        int k = ks * 32 + kqq * 8 + j;
        int c = 32 * wvv + tt * 16 + mm;
        W2P[i] = cvt_elem(W2, (size_t)l * DIM * DIM + (size_t)k * DIM + c, isbf);
        return;
    }
    i -= NW1C;
    if (i >= 5 * NVC) return;
    int seg = i / NVC, k = i - seg * NVC;
    if (seg == 0) bgc[k] = cvt_elem(bg, k, isbf);
    else if (seg == 1) b1c[k] = cvt_elem(b1, k, isbf);
    else if (seg == 2) b2c[k] = cvt_elem(b2, k, isbf);
    else if (seg == 3) n1c[k] = cvt_elem(n1, k, isbf);
    else n2c[k] = cvt_elem(n2, k, isbf);
}

// ---------------- mega: vec-convert(+fragment-pack) + hist + asd_x8 ----------------
__global__ __launch_bounds__(256) void mega_setup(
        const void* x, const void* Wg, const void* W1, const void* W2,
        const void* bg, const void* b1, const void* b2, const void* n1, const void* n2,
        bf16_t* xb, bf16_t* WmixP, bf16_t* W1P, bf16_t* W2P,
        bf16_t* bgc, bf16_t* b1c, bf16_t* b2c, bf16_t* n1c, bf16_t* n2c,
        const int* ei, int* deg,
        const float* vS, const float* vD,
        float* a_s, float* a_d, unsigned short* x8,
        int convBlocks, int histBlocks) {
    int b = (int)blockIdx.x;
    if (b >= convBlocks + histBlocks) {   // asd_x8 part: wave per node
        bool isbf = wave_detect_bf16((const unsigned short*)x);
        int lane = threadIdx.x & 63;
        int n = (b - convBlocks - histBlocks) * 4 + (int)(threadIdx.x >> 6);
        if (n >= N_NODES) return;
        int c = 2 * lane;
        float f0 = raw_elem(x, (size_t)n * DIM + c, isbf);
        float f1 = raw_elem(x, (size_t)n * DIM + c + 1, isbf);
        x8[n * 64 + lane] = enc_fp8_pair(f0, f1);
#pragma unroll
        for (int h = 0; h < NH; ++h) {
            float ps = f0 * vS[h * DIM + c] + f1 * vS[h * DIM + c + 1];
            float pd = f0 * vD[h * DIM + c] + f1 * vD[h * DIM + c + 1];
#pragma unroll
            for (int msk = 1; msk < 64; msk <<= 1) {
                ps += __shfl_xor(ps, msk);
                pd += __shfl_xor(pd, msk);
            }
            if (lane == 0) {
                a_s[n * 4 + h] = ps;
                a_d[n * 4 + h] = pd;
            }
        }
        return;
    }
    if (b >= convBlocks) {   // histogram
        bool is64 = wave_detect_i64(ei);
        int e = (b - convBlocks) * 256 + threadIdx.x;
        if (e < NEDGE) atomicAdd(&deg[edge_dst(ei, e, is64)], 1);
        return;
    }
    bool isbf = wave_detect_bf16((const unsigned short*)x);
    int i = b * 256 + threadIdx.x;
    if (i < NXV) {   // vectorized x -> bf16 convert (16B/lane)
        if (isbf) {
            ((bf16v8*)xb)[i] = ((const bf16v8*)x)[i];
        } else {
            const float4* src = (const float4*)x;
            float4 a = src[2 * i], bq = src[2 * i + 1];
            bf16v8 o;
            o[0] = (bf16_t)a.x;  o[1] = (bf16_t)a.y;
            o[2] = (bf16_t)a.z;  o[3] = (bf16_t)a.w;
            o[4] = (bf16_t)bq.x; o[5] = (bf16_t)bq.y;
            o[6] = (bf16_t)bq.z; o[7] = (bf16_t)bq.w;
            ((bf16v8*)xb)[i] = o;
        }
        return;
    }
    pack_item(i - NXV, isbf, Wg, W1, W2, bg, b1, b2, n1, n2,
              WmixP, W1P, W2P, bgc, b1c, b2c, n1c, n2c);
}

// ---------------- scan: one-pass, 20 nodes per thread, 2 barriers total ----------------
__global__ __launch_bounds__(1024) void scan_kernel(const int* __restrict__ deg,
                                                    int* __restrict__ row_ptr,
                                                    int* __restrict__ cursor) {
    __shared__ int wsum[16];
    int tid = threadIdx.x, lane = tid & 63, wv = tid >> 6;
    int v[20];
    int base = tid * 20;
    int tot = 0;
    if (base < N_NODES) {
        const int4* d4 = reinterpret_cast<const int4*>(deg + base);   // 80B-aligned
#pragma unroll
        for (int j = 0; j < 5; ++j) {
            int4 q = d4[j];
            v[4 * j]     = q.x;
            v[4 * j + 1] = q.y;
            v[4 * j + 2] = q.z;
            v[4 * j + 3] = q.w;
        }
#pragma unroll
        for (int i = 0; i < 20; ++i) tot += v[i];
    }
    int x = tot;   // inclusive wave scan
#pragma unroll
    for (int off = 1; off < 64; off <<= 1) {
        int t = __shfl_up(x, off);
        if (lane >= off) x += t;
    }
    if (lane == 63) wsum[wv] = x;
    __syncthreads();
    if (wv == 0) {
        int s = (lane < 16) ? wsum[lane] : 0;
#pragma unroll
        for (int off = 1; off < 16; off <<= 1) {
            int t = __shfl_up(s, off);
            if (lane >= off) s += t;
        }
        if (lane < 16) wsum[lane] = s;
    }
    __syncthreads();
    int off0 = ((wv == 0) ? 0 : wsum[wv - 1]) + (x - tot);   // exclusive prefix of chunk
    if (tid == 0) row_ptr[0] = 0;
    if (base < N_NODES) {
        int run = off0;
#pragma unroll
        for (int i = 0; i < 20; ++i) {
            run += v[i];
            row_ptr[base + i + 1] = run;
            cursor[base + i] = run - v[i];
        }
    }
}

__global__ void fill_kernel(const int* __restrict__ ei, int* __restrict__ cursor,
                            int* __restrict__ csr_src) {
    bool is64 = wave_detect_i64(ei);
    int e = blockIdx.x * blockDim.x + threadIdx.x;
    if (e < NEDGE) {
        int d = edge_dst(ei, e, is64);
        int pos = atomicAdd(&cursor[d], 1);
        if ((unsigned)pos < (unsigned)NEDGE) csr_src[pos] = edge_src(ei, e, is64);
    }
}

// ---------------- gat_gather: LDS-broadcast edge weights + double-buffered x8 loads ----------------
// Per 64-edge chunk: lanes compute edge weights once into per-wave LDS {w4, s<<6};
// accumulate loop reads them at UNIFORM addresses (hardware broadcast). The 8-edge
// x8 row loads for group u0+8 are ISSUED before the fma of group u0 (latency hiding).
__global__ __launch_bounds__(256) void gat_gather(const int* __restrict__ row_ptr,
                                                  const int* __restrict__ csr_src,
                                                  const float* __restrict__ a_s,
                                                  const float* __restrict__ a_d,
                                                  const unsigned short* __restrict__ x8,
                                                  bf16_t* __restrict__ y) {
    __shared__ float4 wsh[4][64];
    __shared__ int    ssh[4][64];
    int n = (int)((blockIdx.x * blockDim.x + threadIdx.x) >> 6);
    if (n >= N_NODES) return;
    int wv = (int)(threadIdx.x >> 6) & 3;
    int lane = threadIdx.x & 63;
    int beg = row_ptr[n];
    int deg = row_ptr[n + 1] - beg;
    if (deg < 0) deg = 0;
    if (deg > NEDGE) deg = NEDGE;
    if (beg < 0) beg = 0;
    if (beg > NEDGE - deg) beg = NEDGE - deg;

    const float4* a_s4 = reinterpret_cast<const float4*>(a_s);
    const float4 adv = reinterpret_cast<const float4*>(a_d)[n];
    const float4 avs = a_s4[n];
    unsigned short pself = x8[n * 64 + lane];
    float4 wself = {__expf(leaky(avs.x + adv.x)), __expf(leaky(avs.y + adv.y)),
                    __expf(leaky(avs.z + adv.z)), __expf(leaky(avs.w + adv.w))};

    float acc[8];
    {
        f32v2 f = __builtin_amdgcn_cvt_pk_f32_fp8((int)pself, false);
        acc[0] = wself.x * f[0]; acc[1] = wself.x * f[1];
        acc[2] = wself.y * f[0]; acc[3] = wself.y * f[1];
        acc[4] = wself.z * f[0]; acc[5] = wself.z * f[1];
        acc[6] = wself.w * f[0]; acc[7] = wself.w * f[1];
    }

    float4 zl = {0.f, 0.f, 0.f, 0.f};   // per-lane partial Z (each edge counted once)
    for (int c0 = 0; c0 < deg; c0 += 64) {
        int cnt = deg - c0; if (cnt > 64) cnt = 64;
        if (lane < cnt) {
            int s = clamp_node(csr_src[beg + c0 + lane]);
            float4 av = a_s4[s];
            float4 w = {__expf(leaky(av.x + adv.x)), __expf(leaky(av.y + adv.y)),
                        __expf(leaky(av.z + adv.z)), __expf(leaky(av.w + adv.w))};
            zl.x += w.x; zl.y += w.y; zl.z += w.z; zl.w += w.w;
            wsh[wv][lane] = w;
            ssh[wv][lane] = s << 6;   // pre-scaled row base for x8
        }
        // wave-private LDS region: compiler-inserted lgkmcnt orders write->read, no barrier
        unsigned short xeN[8];      // next-group in-flight loads
        {
            int p0 = cnt < 8 ? cnt : 8;
#pragma unroll
            for (int u = 0; u < 8; ++u)
                if (u < p0) xeN[u] = x8[ssh[wv][u] + lane];
        }
        for (int u0 = 0; u0 < cnt; u0 += 8) {
            int uc = cnt - u0; if (uc > 8) uc = 8;
            unsigned short xeC[8];
#pragma unroll
            for (int u = 0; u < 8; ++u) xeC[u] = xeN[u];
            int n0 = u0 + 8;
            int nc = cnt - n0; if (nc > 8) nc = 8;   // may be <= 0
#pragma unroll
            for (int u = 0; u < 8; ++u)
                if (u < nc) xeN[u] = x8[ssh[wv][n0 + u] + lane];   // issue early
#pragma unroll
            for (int u = 0; u < 8; ++u) {
                if (u < uc) {
                    float4 w = wsh[wv][u0 + u];       // uniform address -> broadcast
                    f32v2 f = __builtin_amdgcn_cvt_pk_f32_fp8((int)xeC[u], false);
                    acc[0] += w.x * f[0]; acc[1] += w.x * f[1];
                    acc[2] += w.y * f[0]; acc[3] += w.y * f[1];
                    acc[4] += w.z * f[0]; acc[5] += w.z * f[1];
                    acc[6] += w.w * f[0]; acc[7] += w.w * f[1];
                }
            }
        }
    }
    // Z = wself + sum(zl over lanes), one butterfly
    float4 zr = zl;
#pragma unroll
    for (int msk = 1; msk < 64; msk <<= 1) {
        zr.x += __shfl_xor(zr.x, msk);
        zr.y += __shfl_xor(zr.y, msk);
        zr.z += __shfl_xor(zr.z, msk);
        zr.w += __shfl_xor(zr.w, msk);
    }
    float4 z4 = {wself.x + zr.x, wself.y + zr.y, wself.z + zr.z, wself.w + zr.w};
    float4 ih4 = {1.f / z4.x, 1.f / z4.y, 1.f / z4.z, 1.f / z4.w};
    int c = 2 * lane;
#pragma unroll
    for (int h = 0; h < NH; ++h) {
        float ih = h == 0 ? ih4.x : h == 1 ? ih4.y : h == 2 ? ih4.z : ih4.w;
        bf16v2 o;
        o[0] = (bf16_t)(acc[h * 2 + 0] * ih);
        o[1] = (bf16_t)(acc[h * 2 + 1] * ih);
        *reinterpret_cast<bf16v2*>(&y[(size_t)n * HD + h * DIM + c]) = o;
    }
}

// ---------------- mix_ffn: block = 16 nodes; LDS y-tile + fragment-packed weights ----------------
// MODE 0: writes bf16 xb + next-layer x8/a_s/a_d.  MODE 1: writes f32 d_out.
template <int MODE>
__global__ __launch_bounds__(256) void mix_ffn(
        const bf16_t* __restrict__ y,
        const bf16_t* __restrict__ WmixP, const bf16_t* __restrict__ bg,
        const bf16_t* __restrict__ n1w, const bf16_t* __restrict__ xb,
        const bf16_t* __restrict__ W1P, const bf16_t* __restrict__ b1,
        const bf16_t* __restrict__ W2P, const bf16_t* __restrict__ b2,
        const bf16_t* __restrict__ n2w, void* __restrict__ out,
        const float* __restrict__ vS, const float* __restrict__ vD,
        float* __restrict__ a_s_n, float* __restrict__ a_d_n,
        unsigned char* __restrict__ x8_n) {
    __shared__ bf16_t ylds[16][524];
    __shared__ bf16_t xm[16][140];
    __shared__ float  ssq_p[16][4];
    __shared__ float  asd_p[4][16][8];
    bf16_t (*hh)[140] = reinterpret_cast<bf16_t (*)[140]>(&ylds[0][0]);

    int tile = blockIdx.x;
    int wv = threadIdx.x >> 6;
    int lane = threadIdx.x & 63;
    int m = lane & 15, kq = lane >> 4;

    const bf16_t* ybase = y + (size_t)tile * 16 * HD;
#pragma unroll
    for (int it = 0; it < 8; ++it) {
        int f = it * 2048 + (int)threadIdx.x * 8;
        int row = f >> 9, col = f & 511;
        *reinterpret_cast<bf16v8*>(&ylds[row][col]) =
            *reinterpret_cast<const bf16v8*>(ybase + f);
    }
    __syncthreads();

    f32v4 accm[2];
    accm[0] = (f32v4){0.f, 0.f, 0.f, 0.f};
    accm[1] = (f32v4){0.f, 0.f, 0.f, 0.f};
#pragma unroll
    for (int kk = 0; kk < 16; ++kk) {
        bf16v8 a = *reinterpret_cast<const bf16v8*>(&ylds[m][kk * 32 + kq * 8]);
#pragma unroll
        for (int tt = 0; tt < 2; ++tt) {
            bf16v8 b = *reinterpret_cast<const bf16v8*>(
                WmixP + ((((wv * 16 + kk) * 2 + tt) << 9) + lane * 8));
            accm[tt] = __builtin_amdgcn_mfma_f32_16x16x32_bf16(a, b, accm[tt], 0, 0, 0);
        }
    }
    float vals[2][4];
    {
        float sp[4] = {0.f, 0.f, 0.f, 0.f};
#pragma unroll
        for (int tt = 0; tt < 2; ++tt) {
            int col = 32 * wv + tt * 16 + m;
            float bv = (float)bg[col];
#pragma unroll
            for (int r = 0; r < 4; ++r) {
                int gr = tile * 16 + kq * 4 + r;
                float v = 0.25f * accm[tt][r] + bv + (float)xb[(size_t)gr * DIM + col];
                vals[tt][r] = v;
                sp[r] += v * v;
            }
        }
#pragma unroll
        for (int r = 0; r < 4; ++r) {
            sp[r] += __shfl_xor(sp[r], 1); sp[r] += __shfl_xor(sp[r], 2);
            sp[r] += __shfl_xor(sp[r], 4); sp[r] += __shfl_xor(sp[r], 8);
            if (m == r) ssq_p[kq * 4 + r][wv] = sp[r];
        }
    }
    __syncthreads();
    {
#pragma unroll
        for (int r = 0; r < 4; ++r) {
            int row = kq * 4 + r;
            float s = ssq_p[row][0] + ssq_p[row][1] + ssq_p[row][2] + ssq_p[row][3];
            float scale = rsqrtf(s * (1.f / 128.f) + EPS_RMS);
#pragma unroll
            for (int tt = 0; tt < 2; ++tt) {
                int col = 32 * wv + tt * 16 + m;
                xm[row][col] = (bf16_t)(vals[tt][r] * scale * (float)n1w[col]);
            }
        }
    }
    __syncthreads();

    f32v4 acc1[2];
    acc1[0] = (f32v4){0.f, 0.f, 0.f, 0.f};
    acc1[1] = (f32v4){0.f, 0.f, 0.f, 0.f};
#pragma unroll
    for (int ks = 0; ks < 4; ++ks) {
        bf16v8 a = *reinterpret_cast<const bf16v8*>(&xm[m][ks * 32 + kq * 8]);
#pragma unroll
        for (int tt = 0; tt < 2; ++tt) {
            bf16v8 b = *reinterpret_cast<const bf16v8*>(
                W1P + ((((wv * 4 + ks) * 2 + tt) << 9) + lane * 8));
            acc1[tt] = __builtin_amdgcn_mfma_f32_16x16x32_bf16(a, b, acc1[tt], 0, 0, 0);
        }
    }
#pragma unroll
    for (int tt = 0; tt < 2; ++tt) {
        int col = 32 * wv + tt * 16 + m;
        float bv = (float)b1[col];
#pragma unroll
        for (int r = 0; r < 4; ++r) {
            float v = acc1[tt][r] + bv;
            hh[kq * 4 + r][col] = (bf16_t)(v > 0.f ? v : 0.f);
        }
    }
    __syncthreads();
    f32v4 acc2[2];
    acc2[0] = (f32v4){0.f, 0.f, 0.f, 0.f};
    acc2[1] = (f32v4){0.f, 0.f, 0.f, 0.f};
#pragma unroll
    for (int ks = 0; ks < 4; ++ks) {
        bf16v8 a = *reinterpret_cast<const bf16v8*>(&hh[m][ks * 32 + kq * 8]);
#pragma unroll
        for (int tt = 0; tt < 2; ++tt) {
            bf16v8 b = *reinterpret_cast<const bf16v8*>(
                W2P + ((((wv * 4 + ks) * 2 + tt) << 9) + lane * 8));
            acc2[tt] = __builtin_amdgcn_mfma_f32_16x16x32_bf16(a, b, acc2[tt], 0, 0, 0);
        }
    }
    float vals2[2][4];
    {
        float sp[4] = {0.f, 0.f, 0.f, 0.f};
#pragma unroll
        for (int tt = 0; tt < 2; ++tt) {
            int col = 32 * wv + tt * 16 + m;
            float bv = (float)b2[col];
#pragma unroll
            for (int r = 0; r < 4; ++r) {
                float v = acc2[tt][r] + bv + (float)xm[kq * 4 + r][col];
                vals2[tt][r] = v;
                sp[r] += v * v;
            }
        }
#pragma unroll
        for (int r = 0; r < 4; ++r) {
            sp[r] += __shfl_xor(sp[r], 1); sp[r] += __shfl_xor(sp[r], 2);
            sp[r] += __shfl_xor(sp[r], 4); sp[r] += __shfl_xor(sp[r], 8);
            if (m == r) ssq_p[kq * 4 + r][wv] = sp[r];
        }
    }
    __syncthreads();
    float o2[2][4];
#pragma unroll
    for (int r = 0; r < 4; ++r) {
        int row = kq * 4 + r;
        int gr = tile * 16 + row;
        float s = ssq_p[row][0] + ssq_p[row][1] + ssq_p[row][2] + ssq_p[row][3];
        float scale = rsqrtf(s * (1.f / 128.f) + EPS_RMS);
#pragma unroll
        for (int tt = 0; tt < 2; ++tt) {
            int col = 32 * wv + tt * 16 + m;
            float o = vals2[tt][r] * scale * (float)n2w[col];
            o2[tt][r] = o;
            if (MODE == 1) ((float*)out)[(size_t)gr * DIM + col] = o;
            else {
                ((bf16_t*)out)[(size_t)gr * DIM + col] = (bf16_t)o;
                x8_n[(size_t)gr * DIM + col] = enc_fp8(o);
            }
        }
    }
    if (MODE == 0) {
        float vs0[NH], vs1[NH], vd0[NH], vd1[NH];
        int col0 = 32 * wv + m, col1 = col0 + 16;
#pragma unroll
        for (int h = 0; h < NH; ++h) {
            vs0[h] = vS[h * DIM + col0]; vs1[h] = vS[h * DIM + col1];
            vd0[h] = vD[h * DIM + col0]; vd1[h] = vD[h * DIM + col1];
        }
#pragma unroll
        for (int r = 0; r < 4; ++r) {
#pragma unroll
            for (int h = 0; h < NH; ++h) {
                float ps = o2[0][r] * vs0[h] + o2[1][r] * vs1[h];
                float pd = o2[0][r] * vd0[h] + o2[1][r] * vd1[h];
                ps += __shfl_xor(ps, 1); ps += __shfl_xor(ps, 2);
                ps += __shfl_xor(ps, 4); ps += __shfl_xor(ps, 8);
                pd += __shfl_xor(pd, 1); pd += __shfl_xor(pd, 2);
                pd += __shfl_xor(pd, 4); pd += __shfl_xor(pd, 8);
                if (m == r * 4 + h) {
                    asd_p[wv][kq * 4 + r][h * 2 + 0] = ps;
                    asd_p[wv][kq * 4 + r][h * 2 + 1] = pd;
                }
            }
        }
        __syncthreads();
        int t = threadIdx.x;
        if (t < 128) {
            int row = t >> 3, idx = t & 7;
            float s = asd_p[0][row][idx] + asd_p[1][row][idx]
                    + asd_p[2][row][idx] + asd_p[3][row][idx];
            int gr = tile * 16 + row;
            if (idx & 1) a_d_n[gr * 4 + (idx >> 1)] = s;
            else         a_s_n[gr * 4 + (idx >> 1)] = s;
        }
    }
}

// ---------------- launch (10 dispatches) ----------------
extern "C" void kernel_launch(void* const* d_in, const int* in_sizes, int n_in,
                              void* d_out, int out_size, void* d_ws, size_t ws_size,
                              hipStream_t stream) {
    const void* x_in   = d_in[0];
    const void* W_gat  = d_in[1];
    const void* att_s  = d_in[2];
    const void* att_d  = d_in[3];
    const void* bias_g = d_in[4];
    const void* W1     = d_in[5];
    const void* b1     = d_in[6];
    const void* W2     = d_in[7];
    const void* b2     = d_in[8];
    const void* n1w    = d_in[9];
    const void* n2w    = d_in[10];
    const int*  ei     = (const int*)d_in[11];

    char* ws = (char*)d_ws;
    size_t off = 0;
    auto alloc = [&](size_t bytes) {
        void* p = ws + off;
        off = (off + bytes + 255) & ~(size_t)255;
        return p;
    };
    bf16_t* WmixP   = (bf16_t*)alloc((size_t)LAYERS * HD * DIM * 2);
    bf16_t* W1P     = (bf16_t*)alloc((size_t)LAYERS * DIM * DIM * 2);
    bf16_t* W2P     = (bf16_t*)alloc((size_t)LAYERS * DIM * DIM * 2);
    bf16_t* xb      = (bf16_t*)alloc((size_t)N_NODES * DIM * 2);
    bf16_t* y       = (bf16_t*)alloc((size_t)N_NODES * HD * 2);
    unsigned short* x8a = (unsigned short*)alloc((size_t)N_NODES * DIM);
    unsigned short* x8b = (unsigned short*)alloc((size_t)N_NODES * DIM);
    float*  vS      = (float*)alloc((size_t)LAYERS * HD * 4);
    float*  vD      = (float*)alloc((size_t)LAYERS * HD * 4);
    float*  a_sA    = (float*)alloc((size_t)N_NODES * NH * 4);
    float*  a_dA    = (float*)alloc((size_t)N_NODES * NH * 4);
    float*  a_sB    = (float*)alloc((size_t)N_NODES * NH * 4);
    float*  a_dB    = (float*)alloc((size_t)N_NODES * NH * 4);
    int*    deg     = (int*)alloc((size_t)N_NODES * 4);
    int*    cursor  = (int*)alloc((size_t)N_NODES * 4);
    int*    row_ptr = (int*)alloc((size_t)(N_NODES + 1) * 4);
    int*    csr     = (int*)alloc((size_t)NEDGE * 4);
    bf16_t* bgc     = (bf16_t*)alloc((size_t)LAYERS * DIM * 2);
    bf16_t* b1c     = (bf16_t*)alloc((size_t)LAYERS * DIM * 2);
    bf16_t* b2c     = (bf16_t*)alloc((size_t)LAYERS * DIM * 2);
    bf16_t* n1c     = (bf16_t*)alloc((size_t)LAYERS * DIM * 2);
    bf16_t* n2c     = (bf16_t*)alloc((size_t)LAYERS * DIM * 2);

    // prep_v also zeroes deg (runs before mega_setup's histogram)
    prep_v<<<(LAYERS * DIM * NH * 2 * 64 + 255) / 256, 256, 0, stream>>>(
        x_in, W_gat, att_s, att_d, vS, vD, deg);

    const int NTOT = NXV + NPACK;   // vec8 convert items + pack items
    const int convBlocks = (NTOT + 255) / 256;
    const int histBlocks = (NEDGE + 255) / 256;
    const int asdBlocks  = (N_NODES + 3) / 4;
    mega_setup<<<convBlocks + histBlocks + asdBlocks, 256, 0, stream>>>(
        x_in, W_gat, W1, W2, bias_g, b1, b2, n1w, n2w,
        xb, WmixP, W1P, W2P, bgc, b1c, b2c, n1c, n2c,
        ei, deg, vS, vD, a_sA, a_dA, x8a, convBlocks, histBlocks);

    scan_kernel<<<1, 1024, 0, stream>>>(deg, row_ptr, cursor);
    fill_kernel<<<(NEDGE + 255) / 256, 256, 0, stream>>>(ei, cursor, csr);

    unsigned short* x8cur[2] = {x8a, x8b};
    float* asCur[2] = {a_sA, a_sB};
    float* adCur[2] = {a_dA, a_dB};
    for (int l = 0; l < LAYERS; ++l) {
        int ci = l & 1, ni = (l + 1) & 1;
        gat_gather<<<(N_NODES * 64 + 255) / 256, 256, 0, stream>>>(
            row_ptr, csr, asCur[ci], adCur[ci], x8cur[ci], y);
        if (l < LAYERS - 1) {
            mix_ffn<0><<<NTILES, 256, 0, stream>>>(
                y, WmixP + (size_t)l * HD * DIM, bgc + (size_t)l * DIM,
                n1c + (size_t)l * DIM, xb,
                W1P + (size_t)l * DIM * DIM, b1c + (size_t)l * DIM,
                W2P + (size_t)l * DIM * DIM, b2c + (size_t)l * DIM,
                n2c + (size_t)l * DIM, xb,
                vS + (size_t)(l + 1) * HD, vD + (size_t)(l + 1) * HD,
                asCur[ni], adCur[ni], (unsigned char*)x8cur[ni]);
        } else {
            mix_ffn<1><<<NTILES, 256, 0, stream>>>(
                y, WmixP + (size_t)l * HD * DIM, bgc + (size_t)l * DIM,
                n1c + (size_t)l * DIM, xb,
                W1P + (size_t)l * DIM * DIM, b1c + (size_t)l * DIM,
                W2P + (size_t)l * DIM * DIM, b2c + (size_t)l * DIM,
                n2c + (size_t)l * DIM, d_out,
                nullptr, nullptr, nullptr, nullptr, nullptr);
        }
    }
}

// Round 4
// 291.001 us; speedup vs baseline: 3.5906x; 1.0342x over previous
//
#include <hip/hip_runtime.h>
#include <hip/hip_bf16.h>

#define N_NODES 20000
#define NEDGE   320000
#define DIM     128
#define NH      4
#define HD      512   // NH*DIM
#define LAYERS  3
#define EPS_RMS 1.1920929e-07f
#define SLOPE   0.2f
#define NTILES  (N_NODES >> 4)   // 1250

#define NWGC  (LAYERS * DIM * HD)    // 196608
#define NW1C  (LAYERS * DIM * DIM)   // 49152
#define NVC   (LAYERS * DIM)         // 384
#define NPACK (NWGC + 2 * NW1C + 5 * NVC)   // 296832
#define NXV   (N_NODES * DIM / 8)    // 320000 vec8 items

typedef __bf16 bf16_t;
typedef __bf16 bf16v2 __attribute__((ext_vector_type(2)));
typedef __bf16 bf16v8 __attribute__((ext_vector_type(8)));
typedef float  f32v4  __attribute__((ext_vector_type(4)));
typedef float  f32v2  __attribute__((ext_vector_type(2)));

__device__ __forceinline__ int clamp_node(int s) {
    return ((unsigned)s >= (unsigned)N_NODES) ? 0 : s;
}
__device__ __forceinline__ float leaky(float e) { return e > 0.f ? e : SLOPE * e; }
__device__ __forceinline__ unsigned char enc_fp8(float v) {
    int p = __builtin_amdgcn_cvt_pk_fp8_f32(v, v, 0, false);
    return (unsigned char)(p & 0xff);
}
__device__ __forceinline__ unsigned short enc_fp8_pair(float a, float b) {
    int p = __builtin_amdgcn_cvt_pk_fp8_f32(a, b, 0, false);
    return (unsigned short)(p & 0xffff);
}

// ---- per-wave dtype detection ----
__device__ __forceinline__ bool wave_detect_bf16(const unsigned short* xh) {
    int lane = threadIdx.x & 63;
    unsigned short hw = xh[2 * lane];
    int e = (hw >> 7) & 0xff;
    unsigned long long b = __ballot(e >= 96 && e <= 140);
    return __popcll(b) >= 48;
}
__device__ __forceinline__ bool wave_detect_i64(const int* ei) {
    int lane = threadIdx.x & 63;
    unsigned long long b = __ballot(ei[2 * lane + 1] != 0);
    return b == 0ULL;
}
__device__ __forceinline__ float raw_elem(const void* in, size_t j, bool isbf) {
    return isbf ? (float)((const bf16_t*)in)[j] : ((const float*)in)[j];
}
__device__ __forceinline__ bf16_t cvt_elem(const void* in, size_t j, bool isbf) {
    return isbf ? ((const bf16_t*)in)[j] : (bf16_t)((const float*)in)[j];
}
__device__ __forceinline__ int edge_src(const int* ei, int e, bool is64) {
    return clamp_node(is64 ? ei[2 * e] : ei[e]);
}
__device__ __forceinline__ int edge_dst(const int* ei, int e, bool is64) {
    return clamp_node(is64 ? ei[2 * NEDGE + 2 * e] : ei[NEDGE + e]);
}

// ---------------- prep_v (+ deg zeroing): v_s/v_d[l][h][k] = Wg[l][k][h*128+:]·att[l][h][:] ----------------
__global__ __launch_bounds__(256) void prep_v(const void* x, const void* Wg,
                                              const void* aS, const void* aD,
                                              float* __restrict__ vS, float* __restrict__ vD,
                                              int* __restrict__ deg) {
    int gid = blockIdx.x * 256 + threadIdx.x;
    for (int i = gid; i < N_NODES; i += gridDim.x * 256) deg[i] = 0;
    bool isbf = wave_detect_bf16((const unsigned short*)x);
    int w = gid >> 6;
    if (w >= LAYERS * DIM * NH * 2) return;
    int lane = threadIdx.x & 63;
    int sd = w & 1, h = (w >> 1) & 3, k = (w >> 3) & 127, l = w >> 10;
    const void* att = sd ? aD : aS;
    size_t wbase = (size_t)l * DIM * HD + (size_t)k * HD + h * DIM;
    size_t abase = (size_t)l * NH * DIM + (size_t)h * DIM;
    int c = 2 * lane;
    float p = raw_elem(Wg, wbase + c, isbf) * raw_elem(att, abase + c, isbf)
            + raw_elem(Wg, wbase + c + 1, isbf) * raw_elem(att, abase + c + 1, isbf);
#pragma unroll
    for (int msk = 1; msk < 64; msk <<= 1) p += __shfl_xor(p, msk);
    if (lane == 0) {
        float* dst = sd ? vD : vS;
        dst[l * HD + h * DIM + k] = p;
    }
}

// weight fragment-pack + small-vector convert; item space [0, NPACK)
__device__ __forceinline__ void pack_item(int i, bool isbf,
        const void* Wg, const void* W1, const void* W2,
        const void* bg, const void* b1, const void* b2,
        const void* n1, const void* n2,
        bf16_t* WmixP, bf16_t* W1P, bf16_t* W2P,
        bf16_t* bgc, bf16_t* b1c, bf16_t* b2c, bf16_t* n1c, bf16_t* n2c) {
    if (i < NWGC) {   // Wmix fragment-packed
        int l = i >> 16;
        int r = i & 65535;
        int j = r & 7;
        int lane2 = (r >> 3) & 63;
        int mm = lane2 & 15, kqq = lane2 >> 4;
        int tt = (r >> 9) & 1;
        int kk = (r >> 10) & 15;
        int wvv = r >> 14;
        int kidx = kk * 32 + kqq * 8 + j;          // y-dim 0..511
        int h = kidx >> 7, kp = kidx & 127;        // head, source-dim
        int c = 32 * wvv + tt * 16 + mm;           // output col
        WmixP[i] = cvt_elem(Wg, (size_t)l * DIM * HD + (size_t)kp * HD + h * DIM + c, isbf);
        return;
    }
    i -= NWGC;
    if (i < NW1C) {   // W1 fragment-packed
        int l = i / 16384;
        int r = i & 16383;
        int j = r & 7;
        int lane2 = (r >> 3) & 63;
        int mm = lane2 & 15, kqq = lane2 >> 4;
        int tt = (r >> 9) & 1;
        int ks = (r >> 10) & 3;
        int wvv = r >> 12;
        int k = ks * 32 + kqq * 8 + j;
        int c = 32 * wvv + tt * 16 + mm;
        W1P[i] = cvt_elem(W1, (size_t)l * DIM * DIM + (size_t)k * DIM + c, isbf);
        return;
    }
    i -= NW1C;
    if (i < NW1C) {   // W2 fragment-packed
        int l = i / 16384;
        int r = i & 16383;
        int j = r & 7;
        int lane2 = (r >> 3) & 63;
        int mm = lane2 & 15, kqq = lane2 >> 4;
        int tt = (r >> 9) & 1;
        int ks = (r >> 10) & 3;
        int wvv = r >> 12;
        int k = ks * 32 + kqq * 8 + j;
        int c = 32 * wvv + tt * 16 + mm;
        W2P[i] = cvt_elem(W2, (size_t)l * DIM * DIM + (size_t)k * DIM + c, isbf);
        return;
    }
    i -= NW1C;
    if (i >= 5 * NVC) return;
    int seg = i / NVC, k = i - seg * NVC;
    if (seg == 0) bgc[k] = cvt_elem(bg, k, isbf);
    else if (seg == 1) b1c[k] = cvt_elem(b1, k, isbf);
    else if (seg == 2) b2c[k] = cvt_elem(b2, k, isbf);
    else if (seg == 3) n1c[k] = cvt_elem(n1, k, isbf);
    else n2c[k] = cvt_elem(n2, k, isbf);
}

// ---------------- mega: vec-convert(+fragment-pack) + hist + asd_x8 ----------------
__global__ __launch_bounds__(256) void mega_setup(
        const void* x, const void* Wg, const void* W1, const void* W2,
        const void* bg, const void* b1, const void* b2, const void* n1, const void* n2,
        bf16_t* xb, bf16_t* WmixP, bf16_t* W1P, bf16_t* W2P,
        bf16_t* bgc, bf16_t* b1c, bf16_t* b2c, bf16_t* n1c, bf16_t* n2c,
        const int* ei, int* deg,
        const float* vS, const float* vD,
        float* a_s, float* a_d, unsigned short* x8,
        int convBlocks, int histBlocks) {
    int b = (int)blockIdx.x;
    if (b >= convBlocks + histBlocks) {   // asd_x8 part: wave per node
        bool isbf = wave_detect_bf16((const unsigned short*)x);
        int lane = threadIdx.x & 63;
        int n = (b - convBlocks - histBlocks) * 4 + (int)(threadIdx.x >> 6);
        if (n >= N_NODES) return;
        int c = 2 * lane;
        float f0 = raw_elem(x, (size_t)n * DIM + c, isbf);
        float f1 = raw_elem(x, (size_t)n * DIM + c + 1, isbf);
        x8[n * 64 + lane] = enc_fp8_pair(f0, f1);
#pragma unroll
        for (int h = 0; h < NH; ++h) {
            float ps = f0 * vS[h * DIM + c] + f1 * vS[h * DIM + c + 1];
            float pd = f0 * vD[h * DIM + c] + f1 * vD[h * DIM + c + 1];
#pragma unroll
            for (int msk = 1; msk < 64; msk <<= 1) {
                ps += __shfl_xor(ps, msk);
                pd += __shfl_xor(pd, msk);
            }
            if (lane == 0) {
                a_s[n * 4 + h] = ps;
                a_d[n * 4 + h] = pd;
            }
        }
        return;
    }
    if (b >= convBlocks) {   // histogram
        bool is64 = wave_detect_i64(ei);
        int e = (b - convBlocks) * 256 + threadIdx.x;
        if (e < NEDGE) atomicAdd(&deg[edge_dst(ei, e, is64)], 1);
        return;
    }
    bool isbf = wave_detect_bf16((const unsigned short*)x);
    int i = b * 256 + threadIdx.x;
    if (i < NXV) {   // vectorized x -> bf16 convert (16B/lane)
        if (isbf) {
            ((bf16v8*)xb)[i] = ((const bf16v8*)x)[i];
        } else {
            const float4* src = (const float4*)x;
            float4 a = src[2 * i], bq = src[2 * i + 1];
            bf16v8 o;
            o[0] = (bf16_t)a.x;  o[1] = (bf16_t)a.y;
            o[2] = (bf16_t)a.z;  o[3] = (bf16_t)a.w;
            o[4] = (bf16_t)bq.x; o[5] = (bf16_t)bq.y;
            o[6] = (bf16_t)bq.z; o[7] = (bf16_t)bq.w;
            ((bf16v8*)xb)[i] = o;
        }
        return;
    }
    pack_item(i - NXV, isbf, Wg, W1, W2, bg, b1, b2, n1, n2,
              WmixP, W1P, W2P, bgc, b1c, b2c, n1c, n2c);
}

// ---------------- scan: one-pass, 20 nodes per thread, 2 barriers total ----------------
__global__ __launch_bounds__(1024) void scan_kernel(const int* __restrict__ deg,
                                                    int* __restrict__ row_ptr,
                                                    int* __restrict__ cursor) {
    __shared__ int wsum[16];
    int tid = threadIdx.x, lane = tid & 63, wv = tid >> 6;
    int v[20];
    int base = tid * 20;
    int tot = 0;
    if (base < N_NODES) {
        const int4* d4 = reinterpret_cast<const int4*>(deg + base);   // 80B-aligned
#pragma unroll
        for (int j = 0; j < 5; ++j) {
            int4 q = d4[j];
            v[4 * j]     = q.x;
            v[4 * j + 1] = q.y;
            v[4 * j + 2] = q.z;
            v[4 * j + 3] = q.w;
        }
#pragma unroll
        for (int i = 0; i < 20; ++i) tot += v[i];
    }
    int x = tot;   // inclusive wave scan
#pragma unroll
    for (int off = 1; off < 64; off <<= 1) {
        int t = __shfl_up(x, off);
        if (lane >= off) x += t;
    }
    if (lane == 63) wsum[wv] = x;
    __syncthreads();
    if (wv == 0) {
        int s = (lane < 16) ? wsum[lane] : 0;
#pragma unroll
        for (int off = 1; off < 16; off <<= 1) {
            int t = __shfl_up(s, off);
            if (lane >= off) s += t;
        }
        if (lane < 16) wsum[lane] = s;
    }
    __syncthreads();
    int off0 = ((wv == 0) ? 0 : wsum[wv - 1]) + (x - tot);   // exclusive prefix of chunk
    if (tid == 0) row_ptr[0] = 0;
    if (base < N_NODES) {
        int run = off0;
#pragma unroll
        for (int i = 0; i < 20; ++i) {
            run += v[i];
            row_ptr[base + i + 1] = run;
            cursor[base + i] = run - v[i];
        }
    }
}

__global__ void fill_kernel(const int* __restrict__ ei, int* __restrict__ cursor,
                            int* __restrict__ csr_src) {
    bool is64 = wave_detect_i64(ei);
    int e = blockIdx.x * blockDim.x + threadIdx.x;
    if (e < NEDGE) {
        int d = edge_dst(ei, e, is64);
        int pos = atomicAdd(&cursor[d], 1);
        if ((unsigned)pos < (unsigned)NEDGE) csr_src[pos] = edge_src(ei, e, is64);
    }
}

// ---------------- gather_node_lds: GAT aggregation for one node, output -> LDS row ----------------
// LDS-broadcast edge weights + double-buffered x8 row loads (latency hiding).
__device__ __forceinline__ void gather_node_lds(int n, int lane,
        float4* wshw, int* sshw,
        const int* __restrict__ row_ptr, const int* __restrict__ csr_src,
        const float* __restrict__ a_s, const float* __restrict__ a_d,
        const unsigned short* __restrict__ x8, bf16_t* yrow) {
    int beg = row_ptr[n];
    int deg = row_ptr[n + 1] - beg;
    if (deg < 0) deg = 0;
    if (deg > NEDGE) deg = NEDGE;
    if (beg < 0) beg = 0;
    if (beg > NEDGE - deg) beg = NEDGE - deg;

    const float4* a_s4 = reinterpret_cast<const float4*>(a_s);
    const float4 adv = reinterpret_cast<const float4*>(a_d)[n];
    const float4 avs = a_s4[n];
    unsigned short pself = x8[n * 64 + lane];
    float4 wself = {__expf(leaky(avs.x + adv.x)), __expf(leaky(avs.y + adv.y)),
                    __expf(leaky(avs.z + adv.z)), __expf(leaky(avs.w + adv.w))};

    float acc[8];
    {
        f32v2 f = __builtin_amdgcn_cvt_pk_f32_fp8((int)pself, false);
        acc[0] = wself.x * f[0]; acc[1] = wself.x * f[1];
        acc[2] = wself.y * f[0]; acc[3] = wself.y * f[1];
        acc[4] = wself.z * f[0]; acc[5] = wself.z * f[1];
        acc[6] = wself.w * f[0]; acc[7] = wself.w * f[1];
    }

    float4 zl = {0.f, 0.f, 0.f, 0.f};   // per-lane partial Z (each edge counted once)
    for (int c0 = 0; c0 < deg; c0 += 64) {
        int cnt = deg - c0; if (cnt > 64) cnt = 64;
        if (lane < cnt) {
            int s = clamp_node(csr_src[beg + c0 + lane]);
            float4 av = a_s4[s];
            float4 w = {__expf(leaky(av.x + adv.x)), __expf(leaky(av.y + adv.y)),
                        __expf(leaky(av.z + adv.z)), __expf(leaky(av.w + adv.w))};
            zl.x += w.x; zl.y += w.y; zl.z += w.z; zl.w += w.w;
            wshw[lane] = w;
            sshw[lane] = s << 6;   // pre-scaled row base for x8
        }
        // wave-private LDS region: compiler-inserted lgkmcnt orders write->read, no barrier
        unsigned short xeN[8];      // next-group in-flight loads
        {
            int p0 = cnt < 8 ? cnt : 8;
#pragma unroll
            for (int u = 0; u < 8; ++u)
                if (u < p0) xeN[u] = x8[sshw[u] + lane];
        }
        for (int u0 = 0; u0 < cnt; u0 += 8) {
            int uc = cnt - u0; if (uc > 8) uc = 8;
            unsigned short xeC[8];
#pragma unroll
            for (int u = 0; u < 8; ++u) xeC[u] = xeN[u];
            int n0 = u0 + 8;
            int nc = cnt - n0; if (nc > 8) nc = 8;   // may be <= 0
#pragma unroll
            for (int u = 0; u < 8; ++u)
                if (u < nc) xeN[u] = x8[sshw[n0 + u] + lane];   // issue early
#pragma unroll
            for (int u = 0; u < 8; ++u) {
                if (u < uc) {
                    float4 w = wshw[u0 + u];       // uniform address -> broadcast
                    f32v2 f = __builtin_amdgcn_cvt_pk_f32_fp8((int)xeC[u], false);
                    acc[0] += w.x * f[0]; acc[1] += w.x * f[1];
                    acc[2] += w.y * f[0]; acc[3] += w.y * f[1];
                    acc[4] += w.z * f[0]; acc[5] += w.z * f[1];
                    acc[6] += w.w * f[0]; acc[7] += w.w * f[1];
                }
            }
        }
    }
    // Z = wself + sum(zl over lanes), one butterfly
    float4 zr = zl;
#pragma unroll
    for (int msk = 1; msk < 64; msk <<= 1) {
        zr.x += __shfl_xor(zr.x, msk);
        zr.y += __shfl_xor(zr.y, msk);
        zr.z += __shfl_xor(zr.z, msk);
        zr.w += __shfl_xor(zr.w, msk);
    }
    float4 z4 = {wself.x + zr.x, wself.y + zr.y, wself.z + zr.z, wself.w + zr.w};
    float4 ih4 = {1.f / z4.x, 1.f / z4.y, 1.f / z4.z, 1.f / z4.w};
    int c = 2 * lane;
#pragma unroll
    for (int h = 0; h < NH; ++h) {
        float ih = h == 0 ? ih4.x : h == 1 ? ih4.y : h == 2 ? ih4.z : ih4.w;
        bf16v2 o;
        o[0] = (bf16_t)(acc[h * 2 + 0] * ih);
        o[1] = (bf16_t)(acc[h * 2 + 1] * ih);
        *reinterpret_cast<bf16v2*>(&yrow[h * DIM + c]) = o;   // straight to LDS tile
    }
}

// ---------------- gat_mix: fused per-layer kernel; block = 16 nodes ----------------
// Phase A: 4 waves gather 4 nodes each, writing y rows directly into the LDS tile.
// Phase B: mix+FFN (identical math to the proven mix_ffn).
// MODE 0: writes bf16 xb + next-layer x8/a_s/a_d.  MODE 1: writes f32 d_out.
template <int MODE>
__global__ __launch_bounds__(256) void gat_mix(
        const int* __restrict__ row_ptr, const int* __restrict__ csr_src,
        const float* __restrict__ a_s, const float* __restrict__ a_d,
        const unsigned short* __restrict__ x8,
        const bf16_t* __restrict__ WmixP, const bf16_t* __restrict__ bg,
        const bf16_t* __restrict__ n1w, const bf16_t* __restrict__ xb,
        const bf16_t* __restrict__ W1P, const bf16_t* __restrict__ b1,
        const bf16_t* __restrict__ W2P, const bf16_t* __restrict__ b2,
        const bf16_t* __restrict__ n2w, void* __restrict__ out,
        const float* __restrict__ vS, const float* __restrict__ vD,
        float* __restrict__ a_s_n, float* __restrict__ a_d_n,
        unsigned char* __restrict__ x8_n) {
    __shared__ bf16_t ylds[16][524];
    __shared__ bf16_t xm[16][140];
    __shared__ float  ssq_p[16][4];
    __shared__ float  asd_p[4][16][8];
    __shared__ float4 wsh[4][64];
    __shared__ int    ssh[4][64];
    bf16_t (*hh)[140] = reinterpret_cast<bf16_t (*)[140]>(&ylds[0][0]);

    int tile = blockIdx.x;
    int wv = threadIdx.x >> 6;
    int lane = threadIdx.x & 63;
    int m = lane & 15, kq = lane >> 4;

    // ---- Phase A: gather 16 nodes into ylds (wave wv -> rows wv, wv+4, wv+8, wv+12) ----
    for (int r = wv; r < 16; r += 4)
        gather_node_lds(tile * 16 + r, lane, wsh[wv], ssh[wv],
                        row_ptr, csr_src, a_s, a_d, x8, &ylds[r][0]);
    __syncthreads();

    // ---- Phase B: mix + FFN ----
    f32v4 accm[2];
    accm[0] = (f32v4){0.f, 0.f, 0.f, 0.f};
    accm[1] = (f32v4){0.f, 0.f, 0.f, 0.f};
#pragma unroll
    for (int kk = 0; kk < 16; ++kk) {
        bf16v8 a = *reinterpret_cast<const bf16v8*>(&ylds[m][kk * 32 + kq * 8]);
#pragma unroll
        for (int tt = 0; tt < 2; ++tt) {
            bf16v8 b = *reinterpret_cast<const bf16v8*>(
                WmixP + ((((wv * 16 + kk) * 2 + tt) << 9) + lane * 8));
            accm[tt] = __builtin_amdgcn_mfma_f32_16x16x32_bf16(a, b, accm[tt], 0, 0, 0);
        }
    }
    float vals[2][4];
    {
        float sp[4] = {0.f, 0.f, 0.f, 0.f};
#pragma unroll
        for (int tt = 0; tt < 2; ++tt) {
            int col = 32 * wv + tt * 16 + m;
            float bv = (float)bg[col];
#pragma unroll
            for (int r = 0; r < 4; ++r) {
                int gr = tile * 16 + kq * 4 + r;
                float v = 0.25f * accm[tt][r] + bv + (float)xb[(size_t)gr * DIM + col];
                vals[tt][r] = v;
                sp[r] += v * v;
            }
        }
#pragma unroll
        for (int r = 0; r < 4; ++r) {
            sp[r] += __shfl_xor(sp[r], 1); sp[r] += __shfl_xor(sp[r], 2);
            sp[r] += __shfl_xor(sp[r], 4); sp[r] += __shfl_xor(sp[r], 8);
            if (m == r) ssq_p[kq * 4 + r][wv] = sp[r];
        }
    }
    __syncthreads();
    {
#pragma unroll
        for (int r = 0; r < 4; ++r) {
            int row = kq * 4 + r;
            float s = ssq_p[row][0] + ssq_p[row][1] + ssq_p[row][2] + ssq_p[row][3];
            float scale = rsqrtf(s * (1.f / 128.f) + EPS_RMS);
#pragma unroll
            for (int tt = 0; tt < 2; ++tt) {
                int col = 32 * wv + tt * 16 + m;
                xm[row][col] = (bf16_t)(vals[tt][r] * scale * (float)n1w[col]);
            }
        }
    }
    __syncthreads();

    f32v4 acc1[2];
    acc1[0] = (f32v4){0.f, 0.f, 0.f, 0.f};
    acc1[1] = (f32v4){0.f, 0.f, 0.f, 0.f};
#pragma unroll
    for (int ks = 0; ks < 4; ++ks) {
        bf16v8 a = *reinterpret_cast<const bf16v8*>(&xm[m][ks * 32 + kq * 8]);
#pragma unroll
        for (int tt = 0; tt < 2; ++tt) {
            bf16v8 b = *reinterpret_cast<const bf16v8*>(
                W1P + ((((wv * 4 + ks) * 2 + tt) << 9) + lane * 8));
            acc1[tt] = __builtin_amdgcn_mfma_f32_16x16x32_bf16(a, b, acc1[tt], 0, 0, 0);
        }
    }
#pragma unroll
    for (int tt = 0; tt < 2; ++tt) {
        int col = 32 * wv + tt * 16 + m;
        float bv = (float)b1[col];
#pragma unroll
        for (int r = 0; r < 4; ++r) {
            float v = acc1[tt][r] + bv;
            hh[kq * 4 + r][col] = (bf16_t)(v > 0.f ? v : 0.f);
        }
    }
    __syncthreads();
    f32v4 acc2[2];
    acc2[0] = (f32v4){0.f, 0.f, 0.f, 0.f};
    acc2[1] = (f32v4){0.f, 0.f, 0.f, 0.f};
#pragma unroll
    for (int ks = 0; ks < 4; ++ks) {
        bf16v8 a = *reinterpret_cast<const bf16v8*>(&hh[m][ks * 32 + kq * 8]);
#pragma unroll
        for (int tt = 0; tt < 2; ++tt) {
            bf16v8 b = *reinterpret_cast<const bf16v8*>(
                W2P + ((((wv * 4 + ks) * 2 + tt) << 9) + lane * 8));
            acc2[tt] = __builtin_amdgcn_mfma_f32_16x16x32_bf16(a, b, acc2[tt], 0, 0, 0);
        }
    }
    float vals2[2][4];
    {
        float sp[4] = {0.f, 0.f, 0.f, 0.f};
#pragma unroll
        for (int tt = 0; tt < 2; ++tt) {
            int col = 32 * wv + tt * 16 + m;
            float bv = (float)b2[col];
#pragma unroll
            for (int r = 0; r < 4; ++r) {
                float v = acc2[tt][r] + bv + (float)xm[kq * 4 + r][col];
                vals2[tt][r] = v;
                sp[r] += v * v;
            }
        }
#pragma unroll
        for (int r = 0; r < 4; ++r) {
            sp[r] += __shfl_xor(sp[r], 1); sp[r] += __shfl_xor(sp[r], 2);
            sp[r] += __shfl_xor(sp[r], 4); sp[r] += __shfl_xor(sp[r], 8);
            if (m == r) ssq_p[kq * 4 + r][wv] = sp[r];
        }
    }
    __syncthreads();
    float o2[2][4];
#pragma unroll
    for (int r = 0; r < 4; ++r) {
        int row = kq * 4 + r;
        int gr = tile * 16 + row;
        float s = ssq_p[row][0] + ssq_p[row][1] + ssq_p[row][2] + ssq_p[row][3];
        float scale = rsqrtf(s * (1.f / 128.f) + EPS_RMS);
#pragma unroll
        for (int tt = 0; tt < 2; ++tt) {
            int col = 32 * wv + tt * 16 + m;
            float o = vals2[tt][r] * scale * (float)n2w[col];
            o2[tt][r] = o;
            if (MODE == 1) ((float*)out)[(size_t)gr * DIM + col] = o;
            else {
                ((bf16_t*)out)[(size_t)gr * DIM + col] = (bf16_t)o;
                x8_n[(size_t)gr * DIM + col] = enc_fp8(o);
            }
        }
    }
    if (MODE == 0) {
        float vs0[NH], vs1[NH], vd0[NH], vd1[NH];
        int col0 = 32 * wv + m, col1 = col0 + 16;
#pragma unroll
        for (int h = 0; h < NH; ++h) {
            vs0[h] = vS[h * DIM + col0]; vs1[h] = vS[h * DIM + col1];
            vd0[h] = vD[h * DIM + col0]; vd1[h] = vD[h * DIM + col1];
        }
#pragma unroll
        for (int r = 0; r < 4; ++r) {
#pragma unroll
            for (int h = 0; h < NH; ++h) {
                float ps = o2[0][r] * vs0[h] + o2[1][r] * vs1[h];
                float pd = o2[0][r] * vd0[h] + o2[1][r] * vd1[h];
                ps += __shfl_xor(ps, 1); ps += __shfl_xor(ps, 2);
                ps += __shfl_xor(ps, 4); ps += __shfl_xor(ps, 8);
                pd += __shfl_xor(pd, 1); pd += __shfl_xor(pd, 2);
                pd += __shfl_xor(pd, 4); pd += __shfl_xor(pd, 8);
                if (m == r * 4 + h) {
                    asd_p[wv][kq * 4 + r][h * 2 + 0] = ps;
                    asd_p[wv][kq * 4 + r][h * 2 + 1] = pd;
                }
            }
        }
        __syncthreads();
        int t = threadIdx.x;
        if (t < 128) {
            int row = t >> 3, idx = t & 7;
            float s = asd_p[0][row][idx] + asd_p[1][row][idx]
                    + asd_p[2][row][idx] + asd_p[3][row][idx];
            int gr = tile * 16 + row;
            if (idx & 1) a_d_n[gr * 4 + (idx >> 1)] = s;
            else         a_s_n[gr * 4 + (idx >> 1)] = s;
        }
    }
}

// ---------------- launch (7 dispatches) ----------------
extern "C" void kernel_launch(void* const* d_in, const int* in_sizes, int n_in,
                              void* d_out, int out_size, void* d_ws, size_t ws_size,
                              hipStream_t stream) {
    const void* x_in   = d_in[0];
    const void* W_gat  = d_in[1];
    const void* att_s  = d_in[2];
    const void* att_d  = d_in[3];
    const void* bias_g = d_in[4];
    const void* W1     = d_in[5];
    const void* b1     = d_in[6];
    const void* W2     = d_in[7];
    const void* b2     = d_in[8];
    const void* n1w    = d_in[9];
    const void* n2w    = d_in[10];
    const int*  ei     = (const int*)d_in[11];

    char* ws = (char*)d_ws;
    size_t off = 0;
    auto alloc = [&](size_t bytes) {
        void* p = ws + off;
        off = (off + bytes + 255) & ~(size_t)255;
        return p;
    };
    bf16_t* WmixP   = (bf16_t*)alloc((size_t)LAYERS * HD * DIM * 2);
    bf16_t* W1P     = (bf16_t*)alloc((size_t)LAYERS * DIM * DIM * 2);
    bf16_t* W2P     = (bf16_t*)alloc((size_t)LAYERS * DIM * DIM * 2);
    bf16_t* xb      = (bf16_t*)alloc((size_t)N_NODES * DIM * 2);
    unsigned short* x8a = (unsigned short*)alloc((size_t)N_NODES * DIM);
    unsigned short* x8b = (unsigned short*)alloc((size_t)N_NODES * DIM);
    float*  vS      = (float*)alloc((size_t)LAYERS * HD * 4);
    float*  vD      = (float*)alloc((size_t)LAYERS * HD * 4);
    float*  a_sA    = (float*)alloc((size_t)N_NODES * NH * 4);
    float*  a_dA    = (float*)alloc((size_t)N_NODES * NH * 4);
    float*  a_sB    = (float*)alloc((size_t)N_NODES * NH * 4);
    float*  a_dB    = (float*)alloc((size_t)N_NODES * NH * 4);
    int*    deg     = (int*)alloc((size_t)N_NODES * 4);
    int*    cursor  = (int*)alloc((size_t)N_NODES * 4);
    int*    row_ptr = (int*)alloc((size_t)(N_NODES + 1) * 4);
    int*    csr     = (int*)alloc((size_t)NEDGE * 4);
    bf16_t* bgc     = (bf16_t*)alloc((size_t)LAYERS * DIM * 2);
    bf16_t* b1c     = (bf16_t*)alloc((size_t)LAYERS * DIM * 2);
    bf16_t* b2c     = (bf16_t*)alloc((size_t)LAYERS * DIM * 2);
    bf16_t* n1c     = (bf16_t*)alloc((size_t)LAYERS * DIM * 2);
    bf16_t* n2c     = (bf16_t*)alloc((size_t)LAYERS * DIM * 2);

    // prep_v also zeroes deg (runs before mega_setup's histogram)
    prep_v<<<(LAYERS * DIM * NH * 2 * 64 + 255) / 256, 256, 0, stream>>>(
        x_in, W_gat, att_s, att_d, vS, vD, deg);

    const int NTOT = NXV + NPACK;   // vec8 convert items + pack items
    const int convBlocks = (NTOT + 255) / 256;
    const int histBlocks = (NEDGE + 255) / 256;
    const int asdBlocks  = (N_NODES + 3) / 4;
    mega_setup<<<convBlocks + histBlocks + asdBlocks, 256, 0, stream>>>(
        x_in, W_gat, W1, W2, bias_g, b1, b2, n1w, n2w,
        xb, WmixP, W1P, W2P, bgc, b1c, b2c, n1c, n2c,
        ei, deg, vS, vD, a_sA, a_dA, x8a, convBlocks, histBlocks);

    scan_kernel<<<1, 1024, 0, stream>>>(deg, row_ptr, cursor);
    fill_kernel<<<(NEDGE + 255) / 256, 256, 0, stream>>>(ei, cursor, csr);

    unsigned short* x8cur[2] = {x8a, x8b};
    float* asCur[2] = {a_sA, a_sB};
    float* adCur[2] = {a_dA, a_dB};
    for (int l = 0; l < LAYERS; ++l) {
        int ci = l & 1, ni = (l + 1) & 1;
        if (l < LAYERS - 1) {
            gat_mix<0><<<NTILES, 256, 0, stream>>>(
                row_ptr, csr, asCur[ci], adCur[ci], x8cur[ci],
                WmixP + (size_t)l * HD * DIM, bgc + (size_t)l * DIM,
                n1c + (size_t)l * DIM, xb,
                W1P + (size_t)l * DIM * DIM, b1c + (size_t)l * DIM,
                W2P + (size_t)l * DIM * DIM, b2c + (size_t)l * DIM,
                n2c + (size_t)l * DIM, xb,
                vS + (size_t)(l + 1) * HD, vD + (size_t)(l + 1) * HD,
                asCur[ni], adCur[ni], (unsigned char*)x8cur[ni]);
        } else {
            gat_mix<1><<<NTILES, 256, 0, stream>>>(
                row_ptr, csr, asCur[ci], adCur[ci], x8cur[ci],
                WmixP + (size_t)l * HD * DIM, bgc + (size_t)l * DIM,
                n1c + (size_t)l * DIM, xb,
                W1P + (size_t)l * DIM * DIM, b1c + (size_t)l * DIM,
                W2P + (size_t)l * DIM * DIM, b2c + (size_t)l * DIM,
                n2c + (size_t)l * DIM, d_out,
                nullptr, nullptr, nullptr, nullptr, nullptr);
        }
    }
}